// Round 6
// baseline (779.754 us; speedup 1.0000x reference)
//
#include <hip/hip_runtime.h>
#include <hip/hip_bf16.h>

#define N_NODES 10000
#define N_EDGES 320000
#define PADM    10112   // 79 * 128
#define DOUT3   512

typedef __attribute__((ext_vector_type(4))) float f32x4;
typedef __attribute__((ext_vector_type(8))) short bf16x8;
typedef __attribute__((ext_vector_type(8))) _Float16 f16x8;
typedef __attribute__((ext_vector_type(4))) _Float16 half4;
typedef __attribute__((ext_vector_type(2))) _Float16 half2;

#define GLOAD_LDS16(g, l)                                                        \
  __builtin_amdgcn_global_load_lds(                                              \
      (const __attribute__((address_space(1))) unsigned*)(g),                    \
      (__attribute__((address_space(3))) unsigned*)(l), 16, 0, 0)

__device__ inline unsigned short f2bf(float f) {
  union { float f; unsigned u; } uf; uf.f = f;
  unsigned u = uf.u;
  unsigned r = (u + 0x7fffu + ((u >> 16) & 1u)) >> 16;  // RNE
  return (unsigned short)r;
}

// ---------------- CSR build ----------------
__global__ __launch_bounds__(256) void k_zero(int* p, int n) {
  int i = blockIdx.x * 256 + threadIdx.x;
  if (i < n) p[i] = 0;
}

__global__ __launch_bounds__(256) void k_detect(const unsigned* rowsU32, int* flag) {
  __shared__ int any;
  if (threadIdx.x == 0) any = 0;
  __syncthreads();
  if (rowsU32[2 * threadIdx.x + 1] != 0u) any = 1;
  __syncthreads();
  if (threadIdx.x == 0) *flag = (any == 0) ? 1 : 0;  // 1 => int64
}

__device__ inline int edge_at(const void* p, int i, int is64) {
  return is64 ? (int)((const long long*)p)[i] : ((const int*)p)[i];
}

__global__ __launch_bounds__(256) void k_hist(const void* rows, const int* flag, int* cnt) {
  int i = blockIdx.x * 256 + threadIdx.x;
  if (i >= N_EDGES) return;
  int is64 = *flag;
  atomicAdd(&cnt[edge_at(rows, i, is64)], 1);
}

__global__ __launch_bounds__(256) void k_scan(const int* __restrict__ cnt, int* __restrict__ rp) {
  __shared__ int partial[256];
  const int T = 256;
  int t = threadIdx.x;
  int chunk = (N_NODES + T - 1) / T;
  int start = t * chunk;
  int end = start + chunk; if (end > N_NODES) end = N_NODES;
  int s = 0;
  for (int i = start; i < end && i >= start; ++i) s += cnt[i];
  partial[t] = (start < N_NODES) ? s : 0;
  __syncthreads();
  if (t == 0) {
    int acc = 0;
    for (int i = 0; i < T; ++i) { int v = partial[i]; partial[i] = acc; acc += v; }
  }
  __syncthreads();
  int acc = partial[t];
  for (int i = start; i < end && i >= start; ++i) { rp[i] = acc; acc += cnt[i]; }
  if (t == T - 1) rp[N_NODES] = acc;
}

__global__ __launch_bounds__(256) void k_scatter(const void* rows, const void* cols,
    const float* __restrict__ vals, const int* __restrict__ flag,
    const int* __restrict__ rp, int* cnt2, int* __restrict__ ccol, float* __restrict__ cval) {
  int i = blockIdx.x * 256 + threadIdx.x;
  if (i >= N_EDGES) return;
  int is64 = *flag;
  int r = edge_at(rows, i, is64);
  int c = edge_at(cols, i, is64);
  int pos = rp[r] + atomicAdd(&cnt2[r], 1);
  ccol[pos] = c;
  cval[pos] = vals[i];
}

// ---------------- fused f32 -> f16 for z, w1, w2, w3 ----------------
#define Z4   160000
#define W14  2048
#define W24  8192
#define W34  32768
__global__ __launch_bounds__(256) void k_f2h_all(const float* __restrict__ z, const float* __restrict__ w1,
    const float* __restrict__ w2, const float* __restrict__ w3,
    _Float16* __restrict__ zh, _Float16* __restrict__ w1h,
    _Float16* __restrict__ w2h, _Float16* __restrict__ w3h) {
  int t = blockIdx.x * 256 + threadIdx.x;
  const float* src; _Float16* dst; int idx;
  if (t < Z4)                        { src = z;  dst = zh;  idx = t; }
  else if (t < Z4 + W14)             { src = w1; dst = w1h; idx = t - Z4; }
  else if (t < Z4 + W14 + W24)       { src = w2; dst = w2h; idx = t - Z4 - W14; }
  else if (t < Z4 + W14 + W24 + W34) { src = w3; dst = w3h; idx = t - Z4 - W14 - W24; }
  else return;
  const float4 f = *(const float4*)(src + (size_t)idx * 4);
  half4 h;
  h[0] = (_Float16)f.x; h[1] = (_Float16)f.y; h[2] = (_Float16)f.z; h[3] = (_Float16)f.w;
  *(half4*)(dst + (size_t)idx * 4) = h;
}

// ---------------- fp16 MFMA linear, BK=64: outh = leaky(A[M,K] @ W[Dout,K]^T) ----------------
// staging chunk = 8 rows x 64 halfs (1KB); lane l -> row c*8 + l/8, col (l&7)*8
template <int K>
__global__ __launch_bounds__(256) void k_linh(const _Float16* __restrict__ A,
    const _Float16* __restrict__ W, _Float16* __restrict__ outh,
    int M, int Dout, const int* __restrict__ activeFlag) {
  __shared__ __align__(16) unsigned short As[128 * 64];
  __shared__ __align__(16) unsigned short Bs[128 * 64];
  const int tid = threadIdx.x;
  const int m0 = blockIdx.x * 128, n0 = blockIdx.y * 128;
  const int wave = tid >> 6, lane = tid & 63;
  const int wm = (wave >> 1) << 6;
  const int wn = (wave & 1) << 6;
  const int lr = lane & 15;
  const int lko = (lane >> 4) << 3;

  const int lrow8 = lane >> 3;          // 0..7 within chunk
  const int lcol  = (lane & 7) << 3;    // 0,8,..,56 halfs
  // this wave's 4 A-chunks and 4 B-chunks: c = wave*4 + j
  int arows[4]; const _Float16* gb[4];
  unsigned short *la[4], *lb[4];
#pragma unroll
  for (int j = 0; j < 4; ++j) {
    const int c = wave * 4 + j;
    int ar = m0 + c * 8 + lrow8; if (ar > M - 1) ar = M - 1;   // clamp; stores guarded
    arows[j] = ar;
    gb[j] = W + (size_t)(n0 + c * 8 + lrow8) * K + lcol;
    la[j] = &As[c * 512];
    lb[j] = &Bs[c * 512];
  }

  f32x4 acc[4][4];
#pragma unroll
  for (int i = 0; i < 4; ++i)
#pragma unroll
    for (int j = 0; j < 4; ++j)
#pragma unroll
      for (int q = 0; q < 4; ++q) acc[i][j][q] = 0.f;

  for (int k0 = 0; k0 < K; k0 += 64) {
    __syncthreads();
#pragma unroll
    for (int j = 0; j < 4; ++j) {
      GLOAD_LDS16(A + (size_t)arows[j] * K + k0 + lcol, la[j]);
      GLOAD_LDS16(gb[j] + k0, lb[j]);
    }
    __syncthreads();

#pragma unroll
    for (int kk = 0; kk < 64; kk += 32) {
      f16x8 af[4], bff[4];
#pragma unroll
      for (int f = 0; f < 4; ++f) {
        af[f]  = *(const f16x8*)&As[(wm + f * 16 + lr) * 64 + kk + lko];
        bff[f] = *(const f16x8*)&Bs[(wn + f * 16 + lr) * 64 + kk + lko];
      }
#pragma unroll
      for (int mi = 0; mi < 4; ++mi)
#pragma unroll
        for (int ni = 0; ni < 4; ++ni)
          acc[mi][ni] = __builtin_amdgcn_mfma_f32_16x16x32_f16(af[mi], bff[ni], acc[mi][ni], 0, 0, 0);
    }
  }

  const bool act = (*activeFlag) != 0;
#pragma unroll
  for (int mi = 0; mi < 4; ++mi) {
#pragma unroll
    for (int ni = 0; ni < 4; ++ni) {
      const int col = n0 + wn + ni * 16 + lr;
      const int rbase = m0 + wm + mi * 16 + ((lane >> 4) << 2);
#pragma unroll
      for (int q = 0; q < 4; ++q) {
        const int rr = rbase + q;
        if (rr < M) {
          float v = acc[mi][ni][q];
          if (act && v < 0.f) v *= 0.01f;
          outh[(size_t)rr * Dout + col] = (_Float16)v;
        }
      }
    }
  }
}

// ---------------- CSR spmm, fp16 gather: MODE 0 -> fp16 out; MODE 2 -> fp32 + bf16 out ----------------
template <int D, int MODE>
__global__ __launch_bounds__(128) void k_spmmh(const int* __restrict__ rp,
    const int* __restrict__ ccol, const float* __restrict__ cval,
    const _Float16* __restrict__ sup, _Float16* __restrict__ outh,
    float* __restrict__ outf, unsigned short* __restrict__ outb) {
  constexpr int V = D / 128;
  const int r = blockIdx.x;
  const int d0 = threadIdx.x * V;
  const int s = rp[r], e = rp[r + 1];
  float acc[V];
#pragma unroll
  for (int v = 0; v < V; ++v) acc[v] = 0.f;

  for (int i = s; i < e; ++i) {
    const float w = cval[i];
    const _Float16* src = sup + (size_t)ccol[i] * D + d0;
    if constexpr (V == 4) {
      const half4 x = *(const half4*)src;
#pragma unroll
      for (int v = 0; v < 4; ++v) acc[v] = fmaf(w, (float)x[v], acc[v]);
    } else if constexpr (V == 2) {
      const half2 x = *(const half2*)src;
      acc[0] = fmaf(w, (float)x[0], acc[0]);
      acc[1] = fmaf(w, (float)x[1], acc[1]);
    } else {
      acc[0] = fmaf(w, (float)*src, acc[0]);
    }
  }

  if constexpr (MODE == 0) {
    if constexpr (V == 4) {
      half4 h; h[0] = (_Float16)acc[0]; h[1] = (_Float16)acc[1]; h[2] = (_Float16)acc[2]; h[3] = (_Float16)acc[3];
      *(half4*)(outh + (size_t)r * D + d0) = h;
    } else if constexpr (V == 2) {
      half2 h; h[0] = (_Float16)acc[0]; h[1] = (_Float16)acc[1];
      *(half2*)(outh + (size_t)r * D + d0) = h;
    } else {
      outh[(size_t)r * D + d0] = (_Float16)acc[0];
    }
  } else {
    *(float4*)(outf + (size_t)r * D + d0) = make_float4(acc[0], acc[1], acc[2], acc[3]);
    uint2 u;
    u.x = (unsigned)f2bf(acc[0]) | ((unsigned)f2bf(acc[1]) << 16);
    u.y = (unsigned)f2bf(acc[2]) | ((unsigned)f2bf(acc[3]) << 16);
    *(uint2*)(outb + (size_t)r * 512 + d0) = u;
  }
}

// zero bf16 pad rows 10000..PADM-1
__global__ __launch_bounds__(256) void k_padzero(unsigned short* __restrict__ xb) {
  const int t = blockIdx.x * 256 + threadIdx.x;
  if (t >= (PADM - N_NODES) * 512 / 8) return;
  uint4 z; z.x = z.y = z.z = z.w = 0u;
  *(uint4*)&xb[(size_t)N_NODES * 512 + (size_t)t * 8] = z;
}

// ---------------- final: adj = sigmoid(X @ X^T), bf16 MFMA, BK=64, global_load_lds ----------------
__global__ __launch_bounds__(256) void k_xxt2(const unsigned short* __restrict__ Xb,
                                              float* __restrict__ adj) {
  __shared__ __align__(16) unsigned short As[128 * 64];
  __shared__ __align__(16) unsigned short Bs[128 * 64];
  const int tid = threadIdx.x;
  const int m0 = blockIdx.x * 128, n0 = blockIdx.y * 128;
  const int wave = tid >> 6, lane = tid & 63;
  const int wm = (wave >> 1) << 6;
  const int wn = (wave & 1) << 6;
  const int lr = lane & 15;
  const int lko = (lane >> 4) << 3;

  const int lrow8 = lane >> 3;          // 0..7
  const int lcol  = (lane & 7) << 3;    // halfs
  const unsigned short *gaA[4], *gaB[4];
  unsigned short *la[4], *lb[4];
#pragma unroll
  for (int j = 0; j < 4; ++j) {
    const int c = wave * 4 + j;
    gaA[j] = Xb + (size_t)(m0 + c * 8 + lrow8) * 512 + lcol;
    gaB[j] = Xb + (size_t)(n0 + c * 8 + lrow8) * 512 + lcol;
    la[j] = &As[c * 512];
    lb[j] = &Bs[c * 512];
  }

  f32x4 acc[4][4];
#pragma unroll
  for (int i = 0; i < 4; ++i)
#pragma unroll
    for (int j = 0; j < 4; ++j)
#pragma unroll
      for (int q = 0; q < 4; ++q) acc[i][j][q] = 0.f;

  for (int k0 = 0; k0 < 512; k0 += 64) {
    __syncthreads();
#pragma unroll
    for (int j = 0; j < 4; ++j) {
      GLOAD_LDS16(gaA[j] + k0, la[j]);
      GLOAD_LDS16(gaB[j] + k0, lb[j]);
    }
    __syncthreads();

#pragma unroll
    for (int kk = 0; kk < 64; kk += 32) {
      bf16x8 af[4], bff[4];
#pragma unroll
      for (int f = 0; f < 4; ++f) {
        af[f]  = *(const bf16x8*)&As[(wm + f * 16 + lr) * 64 + kk + lko];
        bff[f] = *(const bf16x8*)&Bs[(wn + f * 16 + lr) * 64 + kk + lko];
      }
#pragma unroll
      for (int mi = 0; mi < 4; ++mi)
#pragma unroll
        for (int ni = 0; ni < 4; ++ni)
          acc[mi][ni] = __builtin_amdgcn_mfma_f32_16x16x32_bf16(af[mi], bff[ni], acc[mi][ni], 0, 0, 0);
    }
  }

#pragma unroll
  for (int mi = 0; mi < 4; ++mi) {
#pragma unroll
    for (int ni = 0; ni < 4; ++ni) {
      const int col = n0 + wn + ni * 16 + lr;
      const int rbase = m0 + wm + mi * 16 + ((lane >> 4) << 2);
      if (col < N_NODES) {
#pragma unroll
        for (int q = 0; q < 4; ++q) {
          const int rr = rbase + q;
          if (rr < N_NODES) {
            const float s = acc[mi][ni][q];
            const float sg = __builtin_amdgcn_rcpf(1.0f + __expf(-s));
            __builtin_nontemporal_store(sg, &adj[(size_t)rr * N_NODES + col]);
          }
        }
      }
    }
  }
}

// ================= fp32 fallback path (used only if ws too small) =================
template <int K>
__global__ __launch_bounds__(256) void k_linear(const float* __restrict__ A,
    const float* __restrict__ W, float* __restrict__ C,
    int M, int Dout, const int* __restrict__ activeFlag) {
  __shared__ __align__(16) float As[16][68];
  __shared__ __align__(16) float Ws[16][68];
  const int m0 = blockIdx.x * 64;
  const int n0 = blockIdx.y * 64;
  const int tid = threadIdx.x;
  const int tx = tid & 15, ty = tid >> 4;
  const int lrow = tid >> 2;
  const int lk = (tid & 3) * 4;
  float acc[4][4];
#pragma unroll
  for (int i = 0; i < 4; ++i)
#pragma unroll
    for (int j = 0; j < 4; ++j) acc[i][j] = 0.f;

  for (int k0 = 0; k0 < K; k0 += 16) {
    float4 va = make_float4(0.f, 0.f, 0.f, 0.f);
    if (m0 + lrow < M) va = *(const float4*)(A + (size_t)(m0 + lrow) * K + k0 + lk);
    float4 vb = *(const float4*)(W + (size_t)(n0 + lrow) * K + k0 + lk);
    __syncthreads();
    As[lk + 0][lrow] = va.x; As[lk + 1][lrow] = va.y; As[lk + 2][lrow] = va.z; As[lk + 3][lrow] = va.w;
    Ws[lk + 0][lrow] = vb.x; Ws[lk + 1][lrow] = vb.y; Ws[lk + 2][lrow] = vb.z; Ws[lk + 3][lrow] = vb.w;
    __syncthreads();
#pragma unroll
    for (int kk = 0; kk < 16; ++kk) {
      const float4 a4 = *(const float4*)&As[kk][ty << 2];
      const float4 b4 = *(const float4*)&Ws[kk][tx << 2];
      const float av[4] = {a4.x, a4.y, a4.z, a4.w};
      const float bv[4] = {b4.x, b4.y, b4.z, b4.w};
#pragma unroll
      for (int i = 0; i < 4; ++i)
#pragma unroll
        for (int j = 0; j < 4; ++j) acc[i][j] = fmaf(av[i], bv[j], acc[i][j]);
    }
  }
  const bool act = (*activeFlag) != 0;
#pragma unroll
  for (int i = 0; i < 4; ++i) {
    const int row = m0 + (ty << 2) + i;
    if (row < M) {
#pragma unroll
      for (int j = 0; j < 4; ++j) {
        float v = acc[i][j];
        if (act && v < 0.f) v *= 0.01f;
        C[(size_t)row * Dout + n0 + (tx << 2) + j] = v;
      }
    }
  }
}

template <int D>
__global__ __launch_bounds__(128) void k_spmm2(const int* __restrict__ rp,
    const int* __restrict__ ccol, const float* __restrict__ cval,
    const float* __restrict__ sup, float* __restrict__ out) {
  constexpr int V = D / 128;
  const int r = blockIdx.x;
  const int d0 = threadIdx.x * V;
  const int s = rp[r], e = rp[r + 1];
  float acc[V];
#pragma unroll
  for (int v = 0; v < V; ++v) acc[v] = 0.f;
  for (int i = s; i < e; ++i) {
    const float w = cval[i];
    const float* src = sup + (size_t)ccol[i] * D + d0;
    if constexpr (V == 4) {
      const float4 x = *(const float4*)src;
      acc[0] = fmaf(w, x.x, acc[0]); acc[1] = fmaf(w, x.y, acc[1]);
      acc[2] = fmaf(w, x.z, acc[2]); acc[3] = fmaf(w, x.w, acc[3]);
    } else if constexpr (V == 2) {
      const float2 x = *(const float2*)src;
      acc[0] = fmaf(w, x.x, acc[0]); acc[1] = fmaf(w, x.y, acc[1]);
    } else {
      acc[0] = fmaf(w, *src, acc[0]);
    }
  }
  float* dst = out + (size_t)r * D + d0;
  if constexpr (V == 4) *(float4*)dst = make_float4(acc[0], acc[1], acc[2], acc[3]);
  else if constexpr (V == 2) *(float2*)dst = make_float2(acc[0], acc[1]);
  else *dst = acc[0];
}

__global__ __launch_bounds__(256) void k_xxt_f32(const float* __restrict__ Xf, float* __restrict__ adj) {
  __shared__ __align__(16) short As[128 * 32];
  __shared__ __align__(16) short Bs[128 * 32];
  const int tid = threadIdx.x;
  const int m0 = blockIdx.x * 128, n0 = blockIdx.y * 128;
  const int wave = tid >> 6, lane = tid & 63;
  const int wm = (wave >> 1) << 6;
  const int wn = (wave & 1) << 6;
  const int lr = lane & 15;
  const int lko = (lane >> 4) << 3;

  f32x4 acc[4][4];
#pragma unroll
  for (int i = 0; i < 4; ++i)
#pragma unroll
    for (int j = 0; j < 4; ++j)
#pragma unroll
      for (int q = 0; q < 4; ++q) acc[i][j][q] = 0.f;

  for (int k0 = 0; k0 < 512; k0 += 32) {
    __syncthreads();
#pragma unroll
    for (int h = 0; h < 2; ++h) {
      const int c = tid + h * 256;
      const int row = c >> 2;
      const int cq = (c & 3) << 3;
      float4 fa0 = make_float4(0, 0, 0, 0), fa1 = fa0, fb0 = fa0, fb1 = fa0;
      const int ga = m0 + row, gb = n0 + row;
      if (ga < N_NODES) {
        fa0 = *(const float4*)(Xf + (size_t)ga * 512 + k0 + cq);
        fa1 = *(const float4*)(Xf + (size_t)ga * 512 + k0 + cq + 4);
      }
      if (gb < N_NODES) {
        fb0 = *(const float4*)(Xf + (size_t)gb * 512 + k0 + cq);
        fb1 = *(const float4*)(Xf + (size_t)gb * 512 + k0 + cq + 4);
      }
      uint4 ua, ub;
      ua.x = (unsigned)f2bf(fa0.x) | ((unsigned)f2bf(fa0.y) << 16);
      ua.y = (unsigned)f2bf(fa0.z) | ((unsigned)f2bf(fa0.w) << 16);
      ua.z = (unsigned)f2bf(fa1.x) | ((unsigned)f2bf(fa1.y) << 16);
      ua.w = (unsigned)f2bf(fa1.z) | ((unsigned)f2bf(fa1.w) << 16);
      ub.x = (unsigned)f2bf(fb0.x) | ((unsigned)f2bf(fb0.y) << 16);
      ub.y = (unsigned)f2bf(fb0.z) | ((unsigned)f2bf(fb0.w) << 16);
      ub.z = (unsigned)f2bf(fb1.x) | ((unsigned)f2bf(fb1.y) << 16);
      ub.w = (unsigned)f2bf(fb1.z) | ((unsigned)f2bf(fb1.w) << 16);
      *(uint4*)&As[row * 32 + cq] = ua;
      *(uint4*)&Bs[row * 32 + cq] = ub;
    }
    __syncthreads();

    bf16x8 af[4], bff[4];
#pragma unroll
    for (int f = 0; f < 4; ++f) {
      af[f]  = *(const bf16x8*)&As[(wm + f * 16 + lr) * 32 + lko];
      bff[f] = *(const bf16x8*)&Bs[(wn + f * 16 + lr) * 32 + lko];
    }
#pragma unroll
    for (int mi = 0; mi < 4; ++mi)
#pragma unroll
      for (int ni = 0; ni < 4; ++ni)
        acc[mi][ni] = __builtin_amdgcn_mfma_f32_16x16x32_bf16(af[mi], bff[ni], acc[mi][ni], 0, 0, 0);
  }

#pragma unroll
  for (int mi = 0; mi < 4; ++mi) {
#pragma unroll
    for (int ni = 0; ni < 4; ++ni) {
      const int col = n0 + wn + ni * 16 + lr;
      const int rbase = m0 + wm + mi * 16 + ((lane >> 4) << 2);
      if (col < N_NODES) {
#pragma unroll
        for (int q = 0; q < 4; ++q) {
          const int rr = rbase + q;
          if (rr < N_NODES) {
            const float s = acc[mi][ni][q];
            adj[(size_t)rr * N_NODES + col] = 1.0f / (1.0f + __expf(-s));
          }
        }
      }
    }
  }
}

// ---------------- host ----------------
extern "C" void kernel_launch(void* const* d_in, const int* in_sizes, int n_in,
                              void* d_out, int out_size, void* d_ws, size_t ws_size,
                              hipStream_t stream) {
  const float* z     = (const float*)d_in[0];
  const void*  arow  = d_in[1];
  const void*  acol  = d_in[2];
  const float* avals = (const float*)d_in[3];
  const float* w1    = (const float*)d_in[4];
  const float* w2    = (const float*)d_in[5];
  const float* w3    = (const float*)d_in[6];
  const int*   activ = (const int*)d_in[7];

  float* out  = (float*)d_out;
  float* xhat = out;                                  // [10000,512]
  float* adj  = out + (size_t)N_NODES * DOUT3;        // [10000,10000]

  // int scratch inside the adj region (dead before k_xxt overwrites it)
  int* iscr  = (int*)(adj + 9000000);
  int* rp    = iscr;                       // 10001 (pad 10016)
  int* cnt   = rp + 10016;
  int* cnt2  = cnt + 10016;
  int* flag  = cnt2 + 10016;               // 1 (pad 16)
  int* ccol  = flag + 16;                  // E
  float* cval = (float*)(ccol + N_EDGES);  // E

  // fp16 scratch in d_ws
  _Float16* wsh = (_Float16*)d_ws;
  size_t off = 0;
  unsigned short* xb = (unsigned short*)d_ws;             off += (size_t)PADM * 512;  // bf16 x_hat
  _Float16* zh  = wsh + off;  off += 640000;
  _Float16* w1h = wsh + off;  off += 8192;
  _Float16* w2h = wsh + off;  off += 32768;
  _Float16* w3h = wsh + off;  off += 131072;
  _Float16* suph = wsh + off; off += (size_t)N_NODES * 512;
  _Float16* x1h = wsh + off;  off += (size_t)N_NODES * 128;
  _Float16* x2h = wsh + off;  off += (size_t)N_NODES * 256;
  const bool useWs = (ws_size >= off * sizeof(_Float16));

  // CSR build
  k_zero<<<(20032 + 255) / 256, 256, 0, stream>>>(cnt, 20032);
  k_detect<<<1, 256, 0, stream>>>((const unsigned*)arow, flag);
  k_hist<<<(N_EDGES + 255) / 256, 256, 0, stream>>>(arow, flag, cnt);
  k_scan<<<1, 256, 0, stream>>>(cnt, rp);
  k_scatter<<<(N_EDGES + 255) / 256, 256, 0, stream>>>(arow, acol, avals, flag, rp, cnt2, ccol, cval);

  if (useWs) {
    // convert inputs to fp16 (single fused launch)
    k_f2h_all<<<(Z4 + W14 + W24 + W34 + 255) / 256, 256, 0, stream>>>(
        z, w1, w2, w3, zh, w1h, w2h, w3h);

    // layer 1
    k_linh<64><<<dim3(79, 1), 256, 0, stream>>>(zh, w1h, suph, N_NODES, 128, activ);
    k_spmmh<128, 0><<<N_NODES, 128, 0, stream>>>(rp, ccol, cval, suph, x1h, nullptr, nullptr);
    // layer 2
    k_linh<128><<<dim3(79, 2), 256, 0, stream>>>(x1h, w2h, suph, N_NODES, 256, activ);
    k_spmmh<256, 0><<<N_NODES, 128, 0, stream>>>(rp, ccol, cval, suph, x2h, nullptr, nullptr);
    // layer 3
    k_linh<256><<<dim3(79, 4), 256, 0, stream>>>(x2h, w3h, suph, N_NODES, 512, activ);
    k_spmmh<512, 2><<<N_NODES, 128, 0, stream>>>(rp, ccol, cval, suph, nullptr, xhat, xb);

    k_padzero<<<28, 256, 0, stream>>>(xb);
    k_xxt2<<<dim3(79, 79), 256, 0, stream>>>(xb, adj);
  } else {
    // fp32 fallback (scratch in adj region)
    float* sup = adj;
    float* x1  = adj + 5120000;
    float* x2  = x1 + 1280000;
    k_linear<64><<<dim3(157, 2), 256, 0, stream>>>(z, w1, sup, N_NODES, 128, activ);
    k_spmm2<128><<<N_NODES, 128, 0, stream>>>(rp, ccol, cval, sup, x1);
    k_linear<128><<<dim3(157, 4), 256, 0, stream>>>(x1, w2, sup, N_NODES, 256, activ);
    k_spmm2<256><<<N_NODES, 128, 0, stream>>>(rp, ccol, cval, sup, x2);
    k_linear<256><<<dim3(157, 8), 256, 0, stream>>>(x2, w3, sup, N_NODES, 512, activ);
    k_spmm2<512><<<N_NODES, 128, 0, stream>>>(rp, ccol, cval, sup, xhat);
    k_xxt_f32<<<dim3(79, 79), 256, 0, stream>>>(xhat, adj);
  }
}

// Round 9
// 776.203 us; speedup vs baseline: 1.0046x; 1.0046x over previous
//
#include <hip/hip_runtime.h>
#include <hip/hip_bf16.h>

#define N_NODES 10000
#define N_EDGES 320000
#define PADM    10240   // 40 * 256 (256^2 final-GEMM tiling)
#define DOUT3   512

typedef __attribute__((ext_vector_type(4))) float f32x4;
typedef __attribute__((ext_vector_type(8))) short bf16x8;
typedef __attribute__((ext_vector_type(8))) _Float16 f16x8;
typedef __attribute__((ext_vector_type(4))) _Float16 half4;
typedef __attribute__((ext_vector_type(2))) _Float16 half2;

#define GLOAD_LDS16(g, l)                                                        \
  __builtin_amdgcn_global_load_lds(                                              \
      (const __attribute__((address_space(1))) unsigned*)(g),                    \
      (__attribute__((address_space(3))) unsigned*)(l), 16, 0, 0)

__device__ inline unsigned short f2bf(float f) {
  union { float f; unsigned u; } uf; uf.f = f;
  unsigned u = uf.u;
  unsigned r = (u + 0x7fffu + ((u >> 16) & 1u)) >> 16;  // RNE
  return (unsigned short)r;
}

// ---------------- CSR build ----------------
__global__ __launch_bounds__(256) void k_zero(int* p, int n) {
  int i = blockIdx.x * 256 + threadIdx.x;
  if (i < n) p[i] = 0;
}

__global__ __launch_bounds__(256) void k_detect(const unsigned* rowsU32, int* flag) {
  __shared__ int any;
  if (threadIdx.x == 0) any = 0;
  __syncthreads();
  if (rowsU32[2 * threadIdx.x + 1] != 0u) any = 1;
  __syncthreads();
  if (threadIdx.x == 0) *flag = (any == 0) ? 1 : 0;  // 1 => int64
}

__device__ inline int edge_at(const void* p, int i, int is64) {
  return is64 ? (int)((const long long*)p)[i] : ((const int*)p)[i];
}

__global__ __launch_bounds__(256) void k_hist(const void* rows, const int* flag, int* cnt) {
  int i = blockIdx.x * 256 + threadIdx.x;
  if (i >= N_EDGES) return;
  int is64 = *flag;
  atomicAdd(&cnt[edge_at(rows, i, is64)], 1);
}

__global__ __launch_bounds__(256) void k_scan(const int* __restrict__ cnt, int* __restrict__ rp) {
  __shared__ int partial[256];
  const int T = 256;
  int t = threadIdx.x;
  int chunk = (N_NODES + T - 1) / T;
  int start = t * chunk;
  int end = start + chunk; if (end > N_NODES) end = N_NODES;
  int s = 0;
  for (int i = start; i < end && i >= start; ++i) s += cnt[i];
  partial[t] = (start < N_NODES) ? s : 0;
  __syncthreads();
  if (t == 0) {
    int acc = 0;
    for (int i = 0; i < T; ++i) { int v = partial[i]; partial[i] = acc; acc += v; }
  }
  __syncthreads();
  int acc = partial[t];
  for (int i = start; i < end && i >= start; ++i) { rp[i] = acc; acc += cnt[i]; }
  if (t == T - 1) rp[N_NODES] = acc;
}

__global__ __launch_bounds__(256) void k_scatter(const void* rows, const void* cols,
    const float* __restrict__ vals, const int* __restrict__ flag,
    const int* __restrict__ rp, int* cnt2, int* __restrict__ ccol, float* __restrict__ cval) {
  int i = blockIdx.x * 256 + threadIdx.x;
  if (i >= N_EDGES) return;
  int is64 = *flag;
  int r = edge_at(rows, i, is64);
  int c = edge_at(cols, i, is64);
  int pos = rp[r] + atomicAdd(&cnt2[r], 1);
  ccol[pos] = c;
  cval[pos] = vals[i];
}

// ---------------- fused f32 -> f16 for z, w1, w2, w3 ----------------
#define Z4   160000
#define W14  2048
#define W24  8192
#define W34  32768
__global__ __launch_bounds__(256) void k_f2h_all(const float* __restrict__ z, const float* __restrict__ w1,
    const float* __restrict__ w2, const float* __restrict__ w3,
    _Float16* __restrict__ zh, _Float16* __restrict__ w1h,
    _Float16* __restrict__ w2h, _Float16* __restrict__ w3h) {
  int t = blockIdx.x * 256 + threadIdx.x;
  const float* src; _Float16* dst; int idx;
  if (t < Z4)                        { src = z;  dst = zh;  idx = t; }
  else if (t < Z4 + W14)             { src = w1; dst = w1h; idx = t - Z4; }
  else if (t < Z4 + W14 + W24)       { src = w2; dst = w2h; idx = t - Z4 - W14; }
  else if (t < Z4 + W14 + W24 + W34) { src = w3; dst = w3h; idx = t - Z4 - W14 - W24; }
  else return;
  const float4 f = *(const float4*)(src + (size_t)idx * 4);
  half4 h;
  h[0] = (_Float16)f.x; h[1] = (_Float16)f.y; h[2] = (_Float16)f.z; h[3] = (_Float16)f.w;
  *(half4*)(dst + (size_t)idx * 4) = h;
}

// ---------------- fp16 MFMA linear, BK=64: outh = leaky(A[M,K] @ W[Dout,K]^T) ----------------
template <int K>
__global__ __launch_bounds__(256) void k_linh(const _Float16* __restrict__ A,
    const _Float16* __restrict__ W, _Float16* __restrict__ outh,
    int M, int Dout, const int* __restrict__ activeFlag) {
  __shared__ __align__(16) unsigned short As[128 * 64];
  __shared__ __align__(16) unsigned short Bs[128 * 64];
  const int tid = threadIdx.x;
  const int m0 = blockIdx.x * 128, n0 = blockIdx.y * 128;
  const int wave = tid >> 6, lane = tid & 63;
  const int wm = (wave >> 1) << 6;
  const int wn = (wave & 1) << 6;
  const int lr = lane & 15;
  const int lko = (lane >> 4) << 3;

  const int lrow8 = lane >> 3;          // 0..7 within chunk
  const int lcol  = (lane & 7) << 3;    // 0,8,..,56 halfs
  int arows[4]; const _Float16* gb[4];
  unsigned short *la[4], *lb[4];
#pragma unroll
  for (int j = 0; j < 4; ++j) {
    const int c = wave * 4 + j;
    int ar = m0 + c * 8 + lrow8; if (ar > M - 1) ar = M - 1;   // clamp; stores guarded
    arows[j] = ar;
    gb[j] = W + (size_t)(n0 + c * 8 + lrow8) * K + lcol;
    la[j] = &As[c * 512];
    lb[j] = &Bs[c * 512];
  }

  f32x4 acc[4][4];
#pragma unroll
  for (int i = 0; i < 4; ++i)
#pragma unroll
    for (int j = 0; j < 4; ++j)
#pragma unroll
      for (int q = 0; q < 4; ++q) acc[i][j][q] = 0.f;

  for (int k0 = 0; k0 < K; k0 += 64) {
    __syncthreads();
#pragma unroll
    for (int j = 0; j < 4; ++j) {
      GLOAD_LDS16(A + (size_t)arows[j] * K + k0 + lcol, la[j]);
      GLOAD_LDS16(gb[j] + k0, lb[j]);
    }
    __syncthreads();

#pragma unroll
    for (int kk = 0; kk < 64; kk += 32) {
      f16x8 af[4], bff[4];
#pragma unroll
      for (int f = 0; f < 4; ++f) {
        af[f]  = *(const f16x8*)&As[(wm + f * 16 + lr) * 64 + kk + lko];
        bff[f] = *(const f16x8*)&Bs[(wn + f * 16 + lr) * 64 + kk + lko];
      }
#pragma unroll
      for (int mi = 0; mi < 4; ++mi)
#pragma unroll
        for (int ni = 0; ni < 4; ++ni)
          acc[mi][ni] = __builtin_amdgcn_mfma_f32_16x16x32_f16(af[mi], bff[ni], acc[mi][ni], 0, 0, 0);
    }
  }

  const bool act = (*activeFlag) != 0;
#pragma unroll
  for (int mi = 0; mi < 4; ++mi) {
#pragma unroll
    for (int ni = 0; ni < 4; ++ni) {
      const int col = n0 + wn + ni * 16 + lr;
      const int rbase = m0 + wm + mi * 16 + ((lane >> 4) << 2);
#pragma unroll
      for (int q = 0; q < 4; ++q) {
        const int rr = rbase + q;
        if (rr < M) {
          float v = acc[mi][ni][q];
          if (act && v < 0.f) v *= 0.01f;
          outh[(size_t)rr * Dout + col] = (_Float16)v;
        }
      }
    }
  }
}

// ---------------- CSR spmm, fp16 gather: MODE 0 -> fp16 out; MODE 2 -> fp32 + bf16 out ----------------
template <int D, int MODE>
__global__ __launch_bounds__(128) void k_spmmh(const int* __restrict__ rp,
    const int* __restrict__ ccol, const float* __restrict__ cval,
    const _Float16* __restrict__ sup, _Float16* __restrict__ outh,
    float* __restrict__ outf, unsigned short* __restrict__ outb) {
  constexpr int V = D / 128;
  const int r = blockIdx.x;
  const int d0 = threadIdx.x * V;
  const int s = rp[r], e = rp[r + 1];
  float acc[V];
#pragma unroll
  for (int v = 0; v < V; ++v) acc[v] = 0.f;

  for (int i = s; i < e; ++i) {
    const float w = cval[i];
    const _Float16* src = sup + (size_t)ccol[i] * D + d0;
    if constexpr (V == 4) {
      const half4 x = *(const half4*)src;
#pragma unroll
      for (int v = 0; v < 4; ++v) acc[v] = fmaf(w, (float)x[v], acc[v]);
    } else if constexpr (V == 2) {
      const half2 x = *(const half2*)src;
      acc[0] = fmaf(w, (float)x[0], acc[0]);
      acc[1] = fmaf(w, (float)x[1], acc[1]);
    } else {
      acc[0] = fmaf(w, (float)*src, acc[0]);
    }
  }

  if constexpr (MODE == 0) {
    if constexpr (V == 4) {
      half4 h; h[0] = (_Float16)acc[0]; h[1] = (_Float16)acc[1]; h[2] = (_Float16)acc[2]; h[3] = (_Float16)acc[3];
      *(half4*)(outh + (size_t)r * D + d0) = h;
    } else if constexpr (V == 2) {
      half2 h; h[0] = (_Float16)acc[0]; h[1] = (_Float16)acc[1];
      *(half2*)(outh + (size_t)r * D + d0) = h;
    } else {
      outh[(size_t)r * D + d0] = (_Float16)acc[0];
    }
  } else {
    *(float4*)(outf + (size_t)r * D + d0) = make_float4(acc[0], acc[1], acc[2], acc[3]);
    uint2 u;
    u.x = (unsigned)f2bf(acc[0]) | ((unsigned)f2bf(acc[1]) << 16);
    u.y = (unsigned)f2bf(acc[2]) | ((unsigned)f2bf(acc[3]) << 16);
    *(uint2*)(outb + (size_t)r * 512 + d0) = u;
  }
}

// zero bf16 pad rows 10000..PADM-1
__global__ __launch_bounds__(256) void k_padzero(unsigned short* __restrict__ xb) {
  const int t = blockIdx.x * 256 + threadIdx.x;   // (PADM-N)*512/8 = 15360
  if (t >= (PADM - N_NODES) * 512 / 8) return;
  uint4 z; z.x = z.y = z.z = z.w = 0u;
  *(uint4*)&xb[(size_t)N_NODES * 512 + (size_t)t * 8] = z;
}

// ---------------- final: adj = sigmoid(X @ X^T), 256^2 tile, 8 waves, BK=32 (32KB LDS), XCD swizzle ----------------
__global__ __launch_bounds__(512) void k_xxt3(const unsigned short* __restrict__ Xb,
                                              float* __restrict__ adj) {
  __shared__ __align__(16) unsigned short As[256 * 32];   // 16 KB
  __shared__ __align__(16) unsigned short Bs[256 * 32];   // 16 KB
  const int tid = threadIdx.x;

  // bijective chunked XCD swizzle: 1600 blocks, 1600 % 8 == 0
  const int bid = blockIdx.x;
  const int swz = (bid & 7) * 200 + (bid >> 3);
  const int m0 = (swz % 40) * 256;
  const int n0 = (swz / 40) * 256;

  const int wave = tid >> 6, lane = tid & 63;
  const int wm = (wave >> 2) << 7;   // 0 / 128
  const int wn = (wave & 3) << 6;    // 0 / 64 / 128 / 192
  const int lr = lane & 15;
  const int lko = (lane >> 4) << 3;  // 0,8,16,24

  // staging: chunk = 16 rows x 32 shorts (1 KB); 16 chunks per matrix; wave w: chunks 2w, 2w+1
  const int c0 = wave * 2;
  const int srow = c0 * 16 + (lane >> 2);      // 0..239 (+16 for second chunk)
  const int scol = (lane & 3) << 3;            // 0,8,16,24
  const unsigned short* gA0 = Xb + (size_t)(m0 + srow) * 512 + scol;
  const unsigned short* gA1 = gA0 + (size_t)16 * 512;
  const unsigned short* gB0 = Xb + (size_t)(n0 + srow) * 512 + scol;
  const unsigned short* gB1 = gB0 + (size_t)16 * 512;
  unsigned short* lA0 = &As[c0 * 512];
  unsigned short* lA1 = &As[(c0 + 1) * 512];
  unsigned short* lB0 = &Bs[c0 * 512];
  unsigned short* lB1 = &Bs[(c0 + 1) * 512];

  f32x4 acc[8][4];
#pragma unroll
  for (int i = 0; i < 8; ++i)
#pragma unroll
    for (int j = 0; j < 4; ++j)
#pragma unroll
      for (int q = 0; q < 4; ++q) acc[i][j][q] = 0.f;

  for (int k0 = 0; k0 < 512; k0 += 32) {
    __syncthreads();
    GLOAD_LDS16(gA0 + k0, lA0);
    GLOAD_LDS16(gA1 + k0, lA1);
    GLOAD_LDS16(gB0 + k0, lB0);
    GLOAD_LDS16(gB1 + k0, lB1);
    __syncthreads();

    bf16x8 bf[4];
#pragma unroll
    for (int ni = 0; ni < 4; ++ni)
      bf[ni] = *(const bf16x8*)&Bs[(wn + ni * 16 + lr) * 32 + lko];
#pragma unroll
    for (int mi = 0; mi < 8; ++mi) {
      const bf16x8 am = *(const bf16x8*)&As[(wm + mi * 16 + lr) * 32 + lko];
#pragma unroll
      for (int ni = 0; ni < 4; ++ni)
        acc[mi][ni] = __builtin_amdgcn_mfma_f32_16x16x32_bf16(am, bf[ni], acc[mi][ni], 0, 0, 0);
    }
  }

#pragma unroll
  for (int mi = 0; mi < 8; ++mi) {
#pragma unroll
    for (int ni = 0; ni < 4; ++ni) {
      const int col = n0 + wn + ni * 16 + lr;
      const int rbase = m0 + wm + mi * 16 + ((lane >> 4) << 2);
      if (col < N_NODES) {
#pragma unroll
        for (int q = 0; q < 4; ++q) {
          const int rr = rbase + q;
          if (rr < N_NODES) {
            const float s = acc[mi][ni][q];
            const float sg = __builtin_amdgcn_rcpf(1.0f + __expf(-s));
            __builtin_nontemporal_store(sg, &adj[(size_t)rr * N_NODES + col]);
          }
        }
      }
    }
  }
}

// ================= fp32 fallback path (used only if ws too small) =================
template <int K>
__global__ __launch_bounds__(256) void k_linear(const float* __restrict__ A,
    const float* __restrict__ W, float* __restrict__ C,
    int M, int Dout, const int* __restrict__ activeFlag) {
  __shared__ __align__(16) float As[16][68];
  __shared__ __align__(16) float Ws[16][68];
  const int m0 = blockIdx.x * 64;
  const int n0 = blockIdx.y * 64;
  const int tid = threadIdx.x;
  const int tx = tid & 15, ty = tid >> 4;
  const int lrow = tid >> 2;
  const int lk = (tid & 3) * 4;
  float acc[4][4];
#pragma unroll
  for (int i = 0; i < 4; ++i)
#pragma unroll
    for (int j = 0; j < 4; ++j) acc[i][j] = 0.f;

  for (int k0 = 0; k0 < K; k0 += 16) {
    float4 va = make_float4(0.f, 0.f, 0.f, 0.f);
    if (m0 + lrow < M) va = *(const float4*)(A + (size_t)(m0 + lrow) * K + k0 + lk);
    float4 vb = *(const float4*)(W + (size_t)(n0 + lrow) * K + k0 + lk);
    __syncthreads();
    As[lk + 0][lrow] = va.x; As[lk + 1][lrow] = va.y; As[lk + 2][lrow] = va.z; As[lk + 3][lrow] = va.w;
    Ws[lk + 0][lrow] = vb.x; Ws[lk + 1][lrow] = vb.y; Ws[lk + 2][lrow] = vb.z; Ws[lk + 3][lrow] = vb.w;
    __syncthreads();
#pragma unroll
    for (int kk = 0; kk < 16; ++kk) {
      const float4 a4 = *(const float4*)&As[kk][ty << 2];
      const float4 b4 = *(const float4*)&Ws[kk][tx << 2];
      const float av[4] = {a4.x, a4.y, a4.z, a4.w};
      const float bv[4] = {b4.x, b4.y, b4.z, b4.w};
#pragma unroll
      for (int i = 0; i < 4; ++i)
#pragma unroll
        for (int j = 0; j < 4; ++j) acc[i][j] = fmaf(av[i], bv[j], acc[i][j]);
    }
  }
  const bool act = (*activeFlag) != 0;
#pragma unroll
  for (int i = 0; i < 4; ++i) {
    const int row = m0 + (ty << 2) + i;
    if (row < M) {
#pragma unroll
      for (int j = 0; j < 4; ++j) {
        float v = acc[i][j];
        if (act && v < 0.f) v *= 0.01f;
        C[(size_t)row * Dout + n0 + (tx << 2) + j] = v;
      }
    }
  }
}

template <int D>
__global__ __launch_bounds__(128) void k_spmm2(const int* __restrict__ rp,
    const int* __restrict__ ccol, const float* __restrict__ cval,
    const float* __restrict__ sup, float* __restrict__ out) {
  constexpr int V = D / 128;
  const int r = blockIdx.x;
  const int d0 = threadIdx.x * V;
  const int s = rp[r], e = rp[r + 1];
  float acc[V];
#pragma unroll
  for (int v = 0; v < V; ++v) acc[v] = 0.f;
  for (int i = s; i < e; ++i) {
    const float w = cval[i];
    const float* src = sup + (size_t)ccol[i] * D + d0;
    if constexpr (V == 4) {
      const float4 x = *(const float4*)src;
      acc[0] = fmaf(w, x.x, acc[0]); acc[1] = fmaf(w, x.y, acc[1]);
      acc[2] = fmaf(w, x.z, acc[2]); acc[3] = fmaf(w, x.w, acc[3]);
    } else if constexpr (V == 2) {
      const float2 x = *(const float2*)src;
      acc[0] = fmaf(w, x.x, acc[0]); acc[1] = fmaf(w, x.y, acc[1]);
    } else {
      acc[0] = fmaf(w, *src, acc[0]);
    }
  }
  float* dst = out + (size_t)r * D + d0;
  if constexpr (V == 4) *(float4*)dst = make_float4(acc[0], acc[1], acc[2], acc[3]);
  else if constexpr (V == 2) *(float2*)dst = make_float2(acc[0], acc[1]);
  else *dst = acc[0];
}

__global__ __launch_bounds__(256) void k_xxt_f32(const float* __restrict__ Xf, float* __restrict__ adj) {
  __shared__ __align__(16) short As[128 * 32];
  __shared__ __align__(16) short Bs[128 * 32];
  const int tid = threadIdx.x;
  const int m0 = blockIdx.x * 128, n0 = blockIdx.y * 128;
  const int wave = tid >> 6, lane = tid & 63;
  const int wm = (wave >> 1) << 6;
  const int wn = (wave & 1) << 6;
  const int lr = lane & 15;
  const int lko = (lane >> 4) << 3;

  f32x4 acc[4][4];
#pragma unroll
  for (int i = 0; i < 4; ++i)
#pragma unroll
    for (int j = 0; j < 4; ++j)
#pragma unroll
      for (int q = 0; q < 4; ++q) acc[i][j][q] = 0.f;

  for (int k0 = 0; k0 < 512; k0 += 32) {
    __syncthreads();
#pragma unroll
    for (int h = 0; h < 2; ++h) {
      const int c = tid + h * 256;
      const int row = c >> 2;
      const int cq = (c & 3) << 3;
      float4 fa0 = make_float4(0, 0, 0, 0), fa1 = fa0, fb0 = fa0, fb1 = fa0;
      const int ga = m0 + row, gb = n0 + row;
      if (ga < N_NODES) {
        fa0 = *(const float4*)(Xf + (size_t)ga * 512 + k0 + cq);
        fa1 = *(const float4*)(Xf + (size_t)ga * 512 + k0 + cq + 4);
      }
      if (gb < N_NODES) {
        fb0 = *(const float4*)(Xf + (size_t)gb * 512 + k0 + cq);
        fb1 = *(const float4*)(Xf + (size_t)gb * 512 + k0 + cq + 4);
      }
      uint4 ua, ub;
      ua.x = (unsigned)f2bf(fa0.x) | ((unsigned)f2bf(fa0.y) << 16);
      ua.y = (unsigned)f2bf(fa0.z) | ((unsigned)f2bf(fa0.w) << 16);
      ua.z = (unsigned)f2bf(fa1.x) | ((unsigned)f2bf(fa1.y) << 16);
      ua.w = (unsigned)f2bf(fa1.z) | ((unsigned)f2bf(fa1.w) << 16);
      ub.x = (unsigned)f2bf(fb0.x) | ((unsigned)f2bf(fb0.y) << 16);
      ub.y = (unsigned)f2bf(fb0.z) | ((unsigned)f2bf(fb0.w) << 16);
      ub.z = (unsigned)f2bf(fb1.x) | ((unsigned)f2bf(fb1.y) << 16);
      ub.w = (unsigned)f2bf(fb1.z) | ((unsigned)f2bf(fb1.w) << 16);
      *(uint4*)&As[row * 32 + cq] = ua;
      *(uint4*)&Bs[row * 32 + cq] = ub;
    }
    __syncthreads();

    bf16x8 af[4], bff[4];
#pragma unroll
    for (int f = 0; f < 4; ++f) {
      af[f]  = *(const bf16x8*)&As[(wm + f * 16 + lr) * 32 + lko];
      bff[f] = *(const bf16x8*)&Bs[(wn + f * 16 + lr) * 32 + lko];
    }
#pragma unroll
    for (int mi = 0; mi < 4; ++mi)
#pragma unroll
      for (int ni = 0; ni < 4; ++ni)
        acc[mi][ni] = __builtin_amdgcn_mfma_f32_16x16x32_bf16(af[mi], bff[ni], acc[mi][ni], 0, 0, 0);
  }

#pragma unroll
  for (int mi = 0; mi < 4; ++mi) {
#pragma unroll
    for (int ni = 0; ni < 4; ++ni) {
      const int col = n0 + wn + ni * 16 + lr;
      const int rbase = m0 + wm + mi * 16 + ((lane >> 4) << 2);
      if (col < N_NODES) {
#pragma unroll
        for (int q = 0; q < 4; ++q) {
          const int rr = rbase + q;
          if (rr < N_NODES) {
            const float s = acc[mi][ni][q];
            adj[(size_t)rr * N_NODES + col] = 1.0f / (1.0f + __expf(-s));
          }
        }
      }
    }
  }
}

// ---------------- host ----------------
extern "C" void kernel_launch(void* const* d_in, const int* in_sizes, int n_in,
                              void* d_out, int out_size, void* d_ws, size_t ws_size,
                              hipStream_t stream) {
  const float* z     = (const float*)d_in[0];
  const void*  arow  = d_in[1];
  const void*  acol  = d_in[2];
  const float* avals = (const float*)d_in[3];
  const float* w1    = (const float*)d_in[4];
  const float* w2    = (const float*)d_in[5];
  const float* w3    = (const float*)d_in[6];
  const int*   activ = (const int*)d_in[7];

  float* out  = (float*)d_out;
  float* xhat = out;                                  // [10000,512]
  float* adj  = out + (size_t)N_NODES * DOUT3;        // [10000,10000]

  // int scratch inside the adj region (dead before k_xxt overwrites it)
  int* iscr  = (int*)(adj + 9000000);
  int* rp    = iscr;                       // 10001 (pad 10016)
  int* cnt   = rp + 10016;
  int* cnt2  = cnt + 10016;
  int* flag  = cnt2 + 10016;               // 1 (pad 16)
  int* ccol  = flag + 16;                  // E
  float* cval = (float*)(ccol + N_EDGES);  // E

  // fp16 scratch in d_ws
  _Float16* wsh = (_Float16*)d_ws;
  size_t off = 0;
  unsigned short* xb = (unsigned short*)d_ws;             off += (size_t)PADM * 512;  // bf16 x_hat
  _Float16* zh  = wsh + off;  off += 640000;
  _Float16* w1h = wsh + off;  off += 8192;
  _Float16* w2h = wsh + off;  off += 32768;
  _Float16* w3h = wsh + off;  off += 131072;
  _Float16* suph = wsh + off; off += (size_t)N_NODES * 512;
  _Float16* x1h = wsh + off;  off += (size_t)N_NODES * 128;
  _Float16* x2h = wsh + off;  off += (size_t)N_NODES * 256;
  const bool useWs = (ws_size >= off * sizeof(_Float16));

  // CSR build
  k_zero<<<(20032 + 255) / 256, 256, 0, stream>>>(cnt, 20032);
  k_detect<<<1, 256, 0, stream>>>((const unsigned*)arow, flag);
  k_hist<<<(N_EDGES + 255) / 256, 256, 0, stream>>>(arow, flag, cnt);
  k_scan<<<1, 256, 0, stream>>>(cnt, rp);
  k_scatter<<<(N_EDGES + 255) / 256, 256, 0, stream>>>(arow, acol, avals, flag, rp, cnt2, ccol, cval);

  if (useWs) {
    // convert inputs to fp16 (single fused launch)
    k_f2h_all<<<(Z4 + W14 + W24 + W34 + 255) / 256, 256, 0, stream>>>(
        z, w1, w2, w3, zh, w1h, w2h, w3h);

    // layer 1
    k_linh<64><<<dim3(79, 1), 256, 0, stream>>>(zh, w1h, suph, N_NODES, 128, activ);
    k_spmmh<128, 0><<<N_NODES, 128, 0, stream>>>(rp, ccol, cval, suph, x1h, nullptr, nullptr);
    // layer 2
    k_linh<128><<<dim3(79, 2), 256, 0, stream>>>(x1h, w2h, suph, N_NODES, 256, activ);
    k_spmmh<256, 0><<<N_NODES, 128, 0, stream>>>(rp, ccol, cval, suph, x2h, nullptr, nullptr);
    // layer 3
    k_linh<256><<<dim3(79, 4), 256, 0, stream>>>(x2h, w3h, suph, N_NODES, 512, activ);
    k_spmmh<512, 2><<<N_NODES, 128, 0, stream>>>(rp, ccol, cval, suph, nullptr, xhat, xb);

    k_padzero<<<60, 256, 0, stream>>>(xb);
    k_xxt3<<<1600, 512, 0, stream>>>(xb, adj);
  } else {
    // fp32 fallback (scratch in adj region)
    float* sup = adj;
    float* x1  = adj + 5120000;
    float* x2  = x1 + 1280000;
    k_linear<64><<<dim3(157, 2), 256, 0, stream>>>(z, w1, sup, N_NODES, 128, activ);
    k_spmm2<128><<<N_NODES, 128, 0, stream>>>(rp, ccol, cval, sup, x1);
    k_linear<128><<<dim3(157, 4), 256, 0, stream>>>(x1, w2, sup, N_NODES, 256, activ);
    k_spmm2<256><<<N_NODES, 128, 0, stream>>>(rp, ccol, cval, sup, x2);
    k_linear<256><<<dim3(157, 8), 256, 0, stream>>>(x2, w3, sup, N_NODES, 512, activ);
    k_spmm2<512><<<N_NODES, 128, 0, stream>>>(rp, ccol, cval, sup, xhat);
    k_xxt_f32<<<dim3(79, 79), 256, 0, stream>>>(xhat, adj);
  }
}

// Round 12
// 747.118 us; speedup vs baseline: 1.0437x; 1.0389x over previous
//
#include <hip/hip_runtime.h>
#include <hip/hip_bf16.h>

#define N_NODES 10000
#define N_EDGES 320000
#define PADM    10240   // 40 * 256 (256^2 final-GEMM tiling)
#define DOUT3   512

typedef __attribute__((ext_vector_type(4))) float f32x4;
typedef __attribute__((ext_vector_type(8))) short bf16x8;
typedef __attribute__((ext_vector_type(8))) _Float16 f16x8;
typedef __attribute__((ext_vector_type(4))) _Float16 half4;
typedef __attribute__((ext_vector_type(2))) _Float16 half2;

#define GLOAD_LDS16(g, l)                                                        \
  __builtin_amdgcn_global_load_lds(                                              \
      (const __attribute__((address_space(1))) unsigned*)(g),                    \
      (__attribute__((address_space(3))) unsigned*)(l), 16, 0, 0)

__device__ inline unsigned short f2bf(float f) {
  union { float f; unsigned u; } uf; uf.f = f;
  unsigned u = uf.u;
  unsigned r = (u + 0x7fffu + ((u >> 16) & 1u)) >> 16;  // RNE
  return (unsigned short)r;
}

// ---------------- CSR build ----------------
// fused: zero cnt/cnt2 (all blocks) + int64-detect (block 0)
__global__ __launch_bounds__(256) void k_zero_detect(int* p, int n,
    const unsigned* rowsU32, int* flag) {
  int i = blockIdx.x * 256 + threadIdx.x;
  if (i < n) p[i] = 0;
  if (blockIdx.x == 0) {
    __shared__ int any;
    if (threadIdx.x == 0) any = 0;
    __syncthreads();
    if (rowsU32[2 * threadIdx.x + 1] != 0u) any = 1;
    __syncthreads();
    if (threadIdx.x == 0) *flag = (any == 0) ? 1 : 0;  // 1 => int64
  }
}

__device__ inline int edge_at(const void* p, int i, int is64) {
  return is64 ? (int)((const long long*)p)[i] : ((const int*)p)[i];
}

__global__ __launch_bounds__(256) void k_hist(const void* rows, const int* flag, int* cnt) {
  int i = blockIdx.x * 256 + threadIdx.x;
  if (i >= N_EDGES) return;
  int is64 = *flag;
  atomicAdd(&cnt[edge_at(rows, i, is64)], 1);
}

__global__ __launch_bounds__(256) void k_scan(const int* __restrict__ cnt, int* __restrict__ rp) {
  __shared__ int partial[256];
  const int T = 256;
  int t = threadIdx.x;
  int chunk = (N_NODES + T - 1) / T;
  int start = t * chunk;
  int end = start + chunk; if (end > N_NODES) end = N_NODES;
  int s = 0;
  for (int i = start; i < end && i >= start; ++i) s += cnt[i];
  partial[t] = (start < N_NODES) ? s : 0;
  __syncthreads();
  if (t == 0) {
    int acc = 0;
    for (int i = 0; i < T; ++i) { int v = partial[i]; partial[i] = acc; acc += v; }
  }
  __syncthreads();
  int acc = partial[t];
  for (int i = start; i < end && i >= start; ++i) { rp[i] = acc; acc += cnt[i]; }
  if (t == T - 1) rp[N_NODES] = acc;
}

__global__ __launch_bounds__(256) void k_scatter(const void* rows, const void* cols,
    const float* __restrict__ vals, const int* __restrict__ flag,
    const int* __restrict__ rp, int* cnt2, int* __restrict__ ccol, float* __restrict__ cval) {
  int i = blockIdx.x * 256 + threadIdx.x;
  if (i >= N_EDGES) return;
  int is64 = *flag;
  int r = edge_at(rows, i, is64);
  int c = edge_at(cols, i, is64);
  int pos = rp[r] + atomicAdd(&cnt2[r], 1);
  ccol[pos] = c;
  cval[pos] = vals[i];
}

// ---------------- fused f32 -> f16 for z, w1, w2, w3  +  bf16 pad-zero ----------------
#define Z4   160000
#define W14  2048
#define W24  8192
#define W34  32768
#define PADZ 15360   // (PADM - N_NODES) * 512 / 8
__global__ __launch_bounds__(256) void k_f2h_all(const float* __restrict__ z, const float* __restrict__ w1,
    const float* __restrict__ w2, const float* __restrict__ w3,
    _Float16* __restrict__ zh, _Float16* __restrict__ w1h,
    _Float16* __restrict__ w2h, _Float16* __restrict__ w3h,
    unsigned short* __restrict__ xb) {
  int t = blockIdx.x * 256 + threadIdx.x;
  const float* src; _Float16* dst; int idx;
  if (t < Z4)                        { src = z;  dst = zh;  idx = t; }
  else if (t < Z4 + W14)             { src = w1; dst = w1h; idx = t - Z4; }
  else if (t < Z4 + W14 + W24)       { src = w2; dst = w2h; idx = t - Z4 - W14; }
  else if (t < Z4 + W14 + W24 + W34) { src = w3; dst = w3h; idx = t - Z4 - W14 - W24; }
  else if (t < Z4 + W14 + W24 + W34 + PADZ) {
    const int pt = t - Z4 - W14 - W24 - W34;
    uint4 zz; zz.x = zz.y = zz.z = zz.w = 0u;
    *(uint4*)&xb[(size_t)N_NODES * 512 + (size_t)pt * 8] = zz;
    return;
  } else return;
  const float4 f = *(const float4*)(src + (size_t)idx * 4);
  half4 h;
  h[0] = (_Float16)f.x; h[1] = (_Float16)f.y; h[2] = (_Float16)f.z; h[3] = (_Float16)f.w;
  *(half4*)(dst + (size_t)idx * 4) = h;
}

// ---------------- fp16 MFMA linear, BK=64: outh = leaky(A[M,K] @ W[Dout,K]^T) ----------------
template <int K>
__global__ __launch_bounds__(256) void k_linh(const _Float16* __restrict__ A,
    const _Float16* __restrict__ W, _Float16* __restrict__ outh,
    int M, int Dout, const int* __restrict__ activeFlag) {
  __shared__ __align__(16) unsigned short As[128 * 64];
  __shared__ __align__(16) unsigned short Bs[128 * 64];
  const int tid = threadIdx.x;
  const int m0 = blockIdx.x * 128, n0 = blockIdx.y * 128;
  const int wave = tid >> 6, lane = tid & 63;
  const int wm = (wave >> 1) << 6;
  const int wn = (wave & 1) << 6;
  const int lr = lane & 15;
  const int lko = (lane >> 4) << 3;

  const int lrow8 = lane >> 3;          // 0..7 within chunk
  const int lcol  = (lane & 7) << 3;    // 0,8,..,56 halfs
  int arows[4]; const _Float16* gb[4];
  unsigned short *la[4], *lb[4];
#pragma unroll
  for (int j = 0; j < 4; ++j) {
    const int c = wave * 4 + j;
    int ar = m0 + c * 8 + lrow8; if (ar > M - 1) ar = M - 1;   // clamp; stores guarded
    arows[j] = ar;
    gb[j] = W + (size_t)(n0 + c * 8 + lrow8) * K + lcol;
    la[j] = &As[c * 512];
    lb[j] = &Bs[c * 512];
  }

  f32x4 acc[4][4];
#pragma unroll
  for (int i = 0; i < 4; ++i)
#pragma unroll
    for (int j = 0; j < 4; ++j)
#pragma unroll
      for (int q = 0; q < 4; ++q) acc[i][j][q] = 0.f;

  for (int k0 = 0; k0 < K; k0 += 64) {
    __syncthreads();
#pragma unroll
    for (int j = 0; j < 4; ++j) {
      GLOAD_LDS16(A + (size_t)arows[j] * K + k0 + lcol, la[j]);
      GLOAD_LDS16(gb[j] + k0, lb[j]);
    }
    __syncthreads();

#pragma unroll
    for (int kk = 0; kk < 64; kk += 32) {
      f16x8 af[4], bff[4];
#pragma unroll
      for (int f = 0; f < 4; ++f) {
        af[f]  = *(const f16x8*)&As[(wm + f * 16 + lr) * 64 + kk + lko];
        bff[f] = *(const f16x8*)&Bs[(wn + f * 16 + lr) * 64 + kk + lko];
      }
#pragma unroll
      for (int mi = 0; mi < 4; ++mi)
#pragma unroll
        for (int ni = 0; ni < 4; ++ni)
          acc[mi][ni] = __builtin_amdgcn_mfma_f32_16x16x32_f16(af[mi], bff[ni], acc[mi][ni], 0, 0, 0);
    }
  }

  const bool act = (*activeFlag) != 0;
#pragma unroll
  for (int mi = 0; mi < 4; ++mi) {
#pragma unroll
    for (int ni = 0; ni < 4; ++ni) {
      const int col = n0 + wn + ni * 16 + lr;
      const int rbase = m0 + wm + mi * 16 + ((lane >> 4) << 2);
#pragma unroll
      for (int q = 0; q < 4; ++q) {
        const int rr = rbase + q;
        if (rr < M) {
          float v = acc[mi][ni][q];
          if (act && v < 0.f) v *= 0.01f;
          outh[(size_t)rr * Dout + col] = (_Float16)v;
        }
      }
    }
  }
}

// ---------------- CSR spmm, fp16 gathers, 2-edge unrolled ----------------
// D=128: 2 rows per block, one wave (64 lanes) per row, half2 per lane
__global__ __launch_bounds__(128) void k_spmm_d128(const int* __restrict__ rp,
    const int* __restrict__ ccol, const float* __restrict__ cval,
    const _Float16* __restrict__ sup, _Float16* __restrict__ outh) {
  const int wid = threadIdx.x >> 6;
  const int lane = threadIdx.x & 63;
  const int r = blockIdx.x * 2 + wid;
  const int d0 = lane * 2;
  const int s = rp[r], e = rp[r + 1];
  float a0x = 0.f, a0y = 0.f, a1x = 0.f, a1y = 0.f;
  int i = s;
  for (; i + 1 < e; i += 2) {
    const float w0 = cval[i], w1 = cval[i + 1];
    const half2 x0 = *(const half2*)(sup + (size_t)ccol[i] * 128 + d0);
    const half2 x1 = *(const half2*)(sup + (size_t)ccol[i + 1] * 128 + d0);
    a0x = fmaf(w0, (float)x0[0], a0x); a0y = fmaf(w0, (float)x0[1], a0y);
    a1x = fmaf(w1, (float)x1[0], a1x); a1y = fmaf(w1, (float)x1[1], a1y);
  }
  if (i < e) {
    const float w0 = cval[i];
    const half2 x0 = *(const half2*)(sup + (size_t)ccol[i] * 128 + d0);
    a0x = fmaf(w0, (float)x0[0], a0x); a0y = fmaf(w0, (float)x0[1], a0y);
  }
  half2 h; h[0] = (_Float16)(a0x + a1x); h[1] = (_Float16)(a0y + a1y);
  *(half2*)(outh + (size_t)r * 128 + d0) = h;
}

// D=256: one row per 128-thread block, half2 per thread
__global__ __launch_bounds__(128) void k_spmm_d256(const int* __restrict__ rp,
    const int* __restrict__ ccol, const float* __restrict__ cval,
    const _Float16* __restrict__ sup, _Float16* __restrict__ outh) {
  const int r = blockIdx.x;
  const int d0 = threadIdx.x * 2;
  const int s = rp[r], e = rp[r + 1];
  float a0x = 0.f, a0y = 0.f, a1x = 0.f, a1y = 0.f;
  int i = s;
  for (; i + 1 < e; i += 2) {
    const float w0 = cval[i], w1 = cval[i + 1];
    const half2 x0 = *(const half2*)(sup + (size_t)ccol[i] * 256 + d0);
    const half2 x1 = *(const half2*)(sup + (size_t)ccol[i + 1] * 256 + d0);
    a0x = fmaf(w0, (float)x0[0], a0x); a0y = fmaf(w0, (float)x0[1], a0y);
    a1x = fmaf(w1, (float)x1[0], a1x); a1y = fmaf(w1, (float)x1[1], a1y);
  }
  if (i < e) {
    const float w0 = cval[i];
    const half2 x0 = *(const half2*)(sup + (size_t)ccol[i] * 256 + d0);
    a0x = fmaf(w0, (float)x0[0], a0x); a0y = fmaf(w0, (float)x0[1], a0y);
  }
  half2 h; h[0] = (_Float16)(a0x + a1x); h[1] = (_Float16)(a0y + a1y);
  *(half2*)(outh + (size_t)r * 256 + d0) = h;
}

// D=512: one row per 128-thread block, half4 per thread; writes fp32 xhat + bf16 xb
__global__ __launch_bounds__(128) void k_spmm_d512(const int* __restrict__ rp,
    const int* __restrict__ ccol, const float* __restrict__ cval,
    const _Float16* __restrict__ sup, float* __restrict__ outf,
    unsigned short* __restrict__ outb) {
  const int r = blockIdx.x;
  const int d0 = threadIdx.x * 4;
  const int s = rp[r], e = rp[r + 1];
  float a0[4] = {0.f, 0.f, 0.f, 0.f}, a1[4] = {0.f, 0.f, 0.f, 0.f};
  int i = s;
  for (; i + 1 < e; i += 2) {
    const float w0 = cval[i], w1 = cval[i + 1];
    const half4 x0 = *(const half4*)(sup + (size_t)ccol[i] * 512 + d0);
    const half4 x1 = *(const half4*)(sup + (size_t)ccol[i + 1] * 512 + d0);
#pragma unroll
    for (int v = 0; v < 4; ++v) {
      a0[v] = fmaf(w0, (float)x0[v], a0[v]);
      a1[v] = fmaf(w1, (float)x1[v], a1[v]);
    }
  }
  if (i < e) {
    const float w0 = cval[i];
    const half4 x0 = *(const half4*)(sup + (size_t)ccol[i] * 512 + d0);
#pragma unroll
    for (int v = 0; v < 4; ++v) a0[v] = fmaf(w0, (float)x0[v], a0[v]);
  }
  const float r0 = a0[0] + a1[0], r1 = a0[1] + a1[1];
  const float r2 = a0[2] + a1[2], r3 = a0[3] + a1[3];
  *(float4*)(outf + (size_t)r * 512 + d0) = make_float4(r0, r1, r2, r3);
  uint2 u;
  u.x = (unsigned)f2bf(r0) | ((unsigned)f2bf(r1) << 16);
  u.y = (unsigned)f2bf(r2) | ((unsigned)f2bf(r3) << 16);
  *(uint2*)(outb + (size_t)r * 512 + d0) = u;
}

// ---------------- final: adj = sigmoid(X @ X^T), 256^2 tile, 8 waves, BK=32 (32KB LDS), XCD swizzle ----------------
__global__ __launch_bounds__(512) void k_xxt3(const unsigned short* __restrict__ Xb,
                                              float* __restrict__ adj) {
  __shared__ __align__(16) unsigned short As[256 * 32];   // 16 KB
  __shared__ __align__(16) unsigned short Bs[256 * 32];   // 16 KB
  const int tid = threadIdx.x;

  // bijective chunked XCD swizzle: 1600 blocks, 1600 % 8 == 0
  const int bid = blockIdx.x;
  const int swz = (bid & 7) * 200 + (bid >> 3);
  const int m0 = (swz % 40) * 256;
  const int n0 = (swz / 40) * 256;

  const int wave = tid >> 6, lane = tid & 63;
  const int wm = (wave >> 2) << 7;   // 0 / 128
  const int wn = (wave & 3) << 6;    // 0 / 64 / 128 / 192
  const int lr = lane & 15;
  const int lko = (lane >> 4) << 3;  // 0,8,16,24

  // staging: chunk = 16 rows x 32 shorts (1 KB); 16 chunks per matrix; wave w: chunks 2w, 2w+1
  const int c0 = wave * 2;
  const int srow = c0 * 16 + (lane >> 2);      // 0..239 (+16 for second chunk)
  const int scol = (lane & 3) << 3;            // 0,8,16,24
  const unsigned short* gA0 = Xb + (size_t)(m0 + srow) * 512 + scol;
  const unsigned short* gA1 = gA0 + (size_t)16 * 512;
  const unsigned short* gB0 = Xb + (size_t)(n0 + srow) * 512 + scol;
  const unsigned short* gB1 = gB0 + (size_t)16 * 512;
  unsigned short* lA0 = &As[c0 * 512];
  unsigned short* lA1 = &As[(c0 + 1) * 512];
  unsigned short* lB0 = &Bs[c0 * 512];
  unsigned short* lB1 = &Bs[(c0 + 1) * 512];

  f32x4 acc[8][4];
#pragma unroll
  for (int i = 0; i < 8; ++i)
#pragma unroll
    for (int j = 0; j < 4; ++j)
#pragma unroll
      for (int q = 0; q < 4; ++q) acc[i][j][q] = 0.f;

  for (int k0 = 0; k0 < 512; k0 += 32) {
    __syncthreads();
    GLOAD_LDS16(gA0 + k0, lA0);
    GLOAD_LDS16(gA1 + k0, lA1);
    GLOAD_LDS16(gB0 + k0, lB0);
    GLOAD_LDS16(gB1 + k0, lB1);
    __syncthreads();

    bf16x8 bf[4];
#pragma unroll
    for (int ni = 0; ni < 4; ++ni)
      bf[ni] = *(const bf16x8*)&Bs[(wn + ni * 16 + lr) * 32 + lko];
#pragma unroll
    for (int mi = 0; mi < 8; ++mi) {
      const bf16x8 am = *(const bf16x8*)&As[(wm + mi * 16 + lr) * 32 + lko];
#pragma unroll
      for (int ni = 0; ni < 4; ++ni)
        acc[mi][ni] = __builtin_amdgcn_mfma_f32_16x16x32_bf16(am, bf[ni], acc[mi][ni], 0, 0, 0);
    }
  }

#pragma unroll
  for (int mi = 0; mi < 8; ++mi) {
#pragma unroll
    for (int ni = 0; ni < 4; ++ni) {
      const int col = n0 + wn + ni * 16 + lr;
      const int rbase = m0 + wm + mi * 16 + ((lane >> 4) << 2);
      if (col < N_NODES) {
#pragma unroll
        for (int q = 0; q < 4; ++q) {
          const int rr = rbase + q;
          if (rr < N_NODES) {
            const float s = acc[mi][ni][q];
            const float sg = __builtin_amdgcn_rcpf(1.0f + __expf(-s));
            __builtin_nontemporal_store(sg, &adj[(size_t)rr * N_NODES + col]);
          }
        }
      }
    }
  }
}

// ================= fp32 fallback path (used only if ws too small) =================
template <int K>
__global__ __launch_bounds__(256) void k_linear(const float* __restrict__ A,
    const float* __restrict__ W, float* __restrict__ C,
    int M, int Dout, const int* __restrict__ activeFlag) {
  __shared__ __align__(16) float As[16][68];
  __shared__ __align__(16) float Ws[16][68];
  const int m0 = blockIdx.x * 64;
  const int n0 = blockIdx.y * 64;
  const int tid = threadIdx.x;
  const int tx = tid & 15, ty = tid >> 4;
  const int lrow = tid >> 2;
  const int lk = (tid & 3) * 4;
  float acc[4][4];
#pragma unroll
  for (int i = 0; i < 4; ++i)
#pragma unroll
    for (int j = 0; j < 4; ++j) acc[i][j] = 0.f;

  for (int k0 = 0; k0 < K; k0 += 16) {
    float4 va = make_float4(0.f, 0.f, 0.f, 0.f);
    if (m0 + lrow < M) va = *(const float4*)(A + (size_t)(m0 + lrow) * K + k0 + lk);
    float4 vb = *(const float4*)(W + (size_t)(n0 + lrow) * K + k0 + lk);
    __syncthreads();
    As[lk + 0][lrow] = va.x; As[lk + 1][lrow] = va.y; As[lk + 2][lrow] = va.z; As[lk + 3][lrow] = va.w;
    Ws[lk + 0][lrow] = vb.x; Ws[lk + 1][lrow] = vb.y; Ws[lk + 2][lrow] = vb.z; Ws[lk + 3][lrow] = vb.w;
    __syncthreads();
#pragma unroll
    for (int kk = 0; kk < 16; ++kk) {
      const float4 a4 = *(const float4*)&As[kk][ty << 2];
      const float4 b4 = *(const float4*)&Ws[kk][tx << 2];
      const float av[4] = {a4.x, a4.y, a4.z, a4.w};
      const float bv[4] = {b4.x, b4.y, b4.z, b4.w};
#pragma unroll
      for (int i = 0; i < 4; ++i)
#pragma unroll
        for (int j = 0; j < 4; ++j) acc[i][j] = fmaf(av[i], bv[j], acc[i][j]);
    }
  }
  const bool act = (*activeFlag) != 0;
#pragma unroll
  for (int i = 0; i < 4; ++i) {
    const int row = m0 + (ty << 2) + i;
    if (row < M) {
#pragma unroll
      for (int j = 0; j < 4; ++j) {
        float v = acc[i][j];
        if (act && v < 0.f) v *= 0.01f;
        C[(size_t)row * Dout + n0 + (tx << 2) + j] = v;
      }
    }
  }
}

template <int D>
__global__ __launch_bounds__(128) void k_spmm2(const int* __restrict__ rp,
    const int* __restrict__ ccol, const float* __restrict__ cval,
    const float* __restrict__ sup, float* __restrict__ out) {
  constexpr int V = D / 128;
  const int r = blockIdx.x;
  const int d0 = threadIdx.x * V;
  const int s = rp[r], e = rp[r + 1];
  float acc[V];
#pragma unroll
  for (int v = 0; v < V; ++v) acc[v] = 0.f;
  for (int i = s; i < e; ++i) {
    const float w = cval[i];
    const float* src = sup + (size_t)ccol[i] * D + d0;
    if constexpr (V == 4) {
      const float4 x = *(const float4*)src;
      acc[0] = fmaf(w, x.x, acc[0]); acc[1] = fmaf(w, x.y, acc[1]);
      acc[2] = fmaf(w, x.z, acc[2]); acc[3] = fmaf(w, x.w, acc[3]);
    } else if constexpr (V == 2) {
      const float2 x = *(const float2*)src;
      acc[0] = fmaf(w, x.x, acc[0]); acc[1] = fmaf(w, x.y, acc[1]);
    } else {
      acc[0] = fmaf(w, *src, acc[0]);
    }
  }
  float* dst = out + (size_t)r * D + d0;
  if constexpr (V == 4) *(float4*)dst = make_float4(acc[0], acc[1], acc[2], acc[3]);
  else if constexpr (V == 2) *(float2*)dst = make_float2(acc[0], acc[1]);
  else *dst = acc[0];
}

__global__ __launch_bounds__(256) void k_xxt_f32(const float* __restrict__ Xf, float* __restrict__ adj) {
  __shared__ __align__(16) short As[128 * 32];
  __shared__ __align__(16) short Bs[128 * 32];
  const int tid = threadIdx.x;
  const int m0 = blockIdx.x * 128, n0 = blockIdx.y * 128;
  const int wave = tid >> 6, lane = tid & 63;
  const int wm = (wave >> 1) << 6;
  const int wn = (wave & 1) << 6;
  const int lr = lane & 15;
  const int lko = (lane >> 4) << 3;

  f32x4 acc[4][4];
#pragma unroll
  for (int i = 0; i < 4; ++i)
#pragma unroll
    for (int j = 0; j < 4; ++j)
#pragma unroll
      for (int q = 0; q < 4; ++q) acc[i][j][q] = 0.f;

  for (int k0 = 0; k0 < 512; k0 += 32) {
    __syncthreads();
#pragma unroll
    for (int h = 0; h < 2; ++h) {
      const int c = tid + h * 256;
      const int row = c >> 2;
      const int cq = (c & 3) << 3;
      float4 fa0 = make_float4(0, 0, 0, 0), fa1 = fa0, fb0 = fa0, fb1 = fa0;
      const int ga = m0 + row, gb = n0 + row;
      if (ga < N_NODES) {
        fa0 = *(const float4*)(Xf + (size_t)ga * 512 + k0 + cq);
        fa1 = *(const float4*)(Xf + (size_t)ga * 512 + k0 + cq + 4);
      }
      if (gb < N_NODES) {
        fb0 = *(const float4*)(Xf + (size_t)gb * 512 + k0 + cq);
        fb1 = *(const float4*)(Xf + (size_t)gb * 512 + k0 + cq + 4);
      }
      uint4 ua, ub;
      ua.x = (unsigned)f2bf(fa0.x) | ((unsigned)f2bf(fa0.y) << 16);
      ua.y = (unsigned)f2bf(fa0.z) | ((unsigned)f2bf(fa0.w) << 16);
      ua.z = (unsigned)f2bf(fa1.x) | ((unsigned)f2bf(fa1.y) << 16);
      ua.w = (unsigned)f2bf(fa1.z) | ((unsigned)f2bf(fa1.w) << 16);
      ub.x = (unsigned)f2bf(fb0.x) | ((unsigned)f2bf(fb0.y) << 16);
      ub.y = (unsigned)f2bf(fb0.z) | ((unsigned)f2bf(fb0.w) << 16);
      ub.z = (unsigned)f2bf(fb1.x) | ((unsigned)f2bf(fb1.y) << 16);
      ub.w = (unsigned)f2bf(fb1.z) | ((unsigned)f2bf(fb1.w) << 16);
      *(uint4*)&As[row * 32 + cq] = ua;
      *(uint4*)&Bs[row * 32 + cq] = ub;
    }
    __syncthreads();

    bf16x8 af[4], bff[4];
#pragma unroll
    for (int f = 0; f < 4; ++f) {
      af[f]  = *(const bf16x8*)&As[(wm + f * 16 + lr) * 32 + lko];
      bff[f] = *(const bf16x8*)&Bs[(wn + f * 16 + lr) * 32 + lko];
    }
#pragma unroll
    for (int mi = 0; mi < 4; ++mi)
#pragma unroll
      for (int ni = 0; ni < 4; ++ni)
        acc[mi][ni] = __builtin_amdgcn_mfma_f32_16x16x32_bf16(af[mi], bff[ni], acc[mi][ni], 0, 0, 0);
  }

#pragma unroll
  for (int mi = 0; mi < 4; ++mi) {
#pragma unroll
    for (int ni = 0; ni < 4; ++ni) {
      const int col = n0 + wn + ni * 16 + lr;
      const int rbase = m0 + wm + mi * 16 + ((lane >> 4) << 2);
      if (col < N_NODES) {
#pragma unroll
        for (int q = 0; q < 4; ++q) {
          const int rr = rbase + q;
          if (rr < N_NODES) {
            const float s = acc[mi][ni][q];
            adj[(size_t)rr * N_NODES + col] = 1.0f / (1.0f + __expf(-s));
          }
        }
      }
    }
  }
}

// ---------------- host ----------------
extern "C" void kernel_launch(void* const* d_in, const int* in_sizes, int n_in,
                              void* d_out, int out_size, void* d_ws, size_t ws_size,
                              hipStream_t stream) {
  const float* z     = (const float*)d_in[0];
  const void*  arow  = d_in[1];
  const void*  acol  = d_in[2];
  const float* avals = (const float*)d_in[3];
  const float* w1    = (const float*)d_in[4];
  const float* w2    = (const float*)d_in[5];
  const float* w3    = (const float*)d_in[6];
  const int*   activ = (const int*)d_in[7];

  float* out  = (float*)d_out;
  float* xhat = out;                                  // [10000,512]
  float* adj  = out + (size_t)N_NODES * DOUT3;        // [10000,10000]

  // int scratch inside the adj region (dead before k_xxt overwrites it)
  int* iscr  = (int*)(adj + 9000000);
  int* rp    = iscr;                       // 10001 (pad 10016)
  int* cnt   = rp + 10016;
  int* cnt2  = cnt + 10016;
  int* flag  = cnt2 + 10016;               // 1 (pad 16)
  int* ccol  = flag + 16;                  // E
  float* cval = (float*)(ccol + N_EDGES);  // E

  // fp16 scratch in d_ws
  _Float16* wsh = (_Float16*)d_ws;
  size_t off = 0;
  unsigned short* xb = (unsigned short*)d_ws;             off += (size_t)PADM * 512;  // bf16 x_hat
  _Float16* zh  = wsh + off;  off += 640000;
  _Float16* w1h = wsh + off;  off += 8192;
  _Float16* w2h = wsh + off;  off += 32768;
  _Float16* w3h = wsh + off;  off += 131072;
  _Float16* suph = wsh + off; off += (size_t)N_NODES * 512;
  _Float16* x1h = wsh + off;  off += (size_t)N_NODES * 128;
  _Float16* x2h = wsh + off;  off += (size_t)N_NODES * 256;
  const bool useWs = (ws_size >= off * sizeof(_Float16));

  // CSR build (fused zero+detect)
  k_zero_detect<<<(20032 + 255) / 256, 256, 0, stream>>>(cnt, 20032, (const unsigned*)arow, flag);
  k_hist<<<(N_EDGES + 255) / 256, 256, 0, stream>>>(arow, flag, cnt);
  k_scan<<<1, 256, 0, stream>>>(cnt, rp);
  k_scatter<<<(N_EDGES + 255) / 256, 256, 0, stream>>>(arow, acol, avals, flag, rp, cnt2, ccol, cval);

  if (useWs) {
    // convert inputs to fp16 + zero bf16 pad rows (single fused launch)
    k_f2h_all<<<(Z4 + W14 + W24 + W34 + PADZ + 255) / 256, 256, 0, stream>>>(
        z, w1, w2, w3, zh, w1h, w2h, w3h, xb);

    // layer 1
    k_linh<64><<<dim3(79, 1), 256, 0, stream>>>(zh, w1h, suph, N_NODES, 128, activ);
    k_spmm_d128<<<N_NODES / 2, 128, 0, stream>>>(rp, ccol, cval, suph, x1h);
    // layer 2
    k_linh<128><<<dim3(79, 2), 256, 0, stream>>>(x1h, w2h, suph, N_NODES, 256, activ);
    k_spmm_d256<<<N_NODES, 128, 0, stream>>>(rp, ccol, cval, suph, x2h);
    // layer 3
    k_linh<256><<<dim3(79, 4), 256, 0, stream>>>(x2h, w3h, suph, N_NODES, 512, activ);
    k_spmm_d512<<<N_NODES, 128, 0, stream>>>(rp, ccol, cval, suph, xhat, xb);

    k_xxt3<<<1600, 512, 0, stream>>>(xb, adj);
  } else {
    // fp32 fallback (scratch in adj region)
    float* sup = adj;
    float* x1  = adj + 5120000;
    float* x2  = x1 + 1280000;
    k_linear<64><<<dim3(157, 2), 256, 0, stream>>>(z, w1, sup, N_NODES, 128, activ);
    k_spmm2<128><<<N_NODES, 128, 0, stream>>>(rp, ccol, cval, sup, x1);
    k_linear<128><<<dim3(157, 4), 256, 0, stream>>>(x1, w2, sup, N_NODES, 256, activ);
    k_spmm2<256><<<N_NODES, 128, 0, stream>>>(rp, ccol, cval, sup, x2);
    k_linear<256><<<dim3(157, 8), 256, 0, stream>>>(x2, w3, sup, N_NODES, 512, activ);
    k_spmm2<512><<<N_NODES, 128, 0, stream>>>(rp, ccol, cval, sup, xhat);
    k_xxt_f32<<<dim3(79, 79), 256, 0, stream>>>(xhat, adj);
  }
}

// Round 13
// 736.327 us; speedup vs baseline: 1.0590x; 1.0147x over previous
//
#include <hip/hip_runtime.h>
#include <hip/hip_bf16.h>

#define N_NODES 10000
#define N_EDGES 320000
#define PADM    10240   // 40 * 256 (256^2 final-GEMM tiling)
#define DOUT3   512

typedef __attribute__((ext_vector_type(4))) float f32x4;
typedef __attribute__((ext_vector_type(8))) short bf16x8;
typedef __attribute__((ext_vector_type(8))) _Float16 f16x8;
typedef __attribute__((ext_vector_type(4))) _Float16 half4;
typedef __attribute__((ext_vector_type(2))) _Float16 half2;

#define GLOAD_LDS16(g, l)                                                        \
  __builtin_amdgcn_global_load_lds(                                              \
      (const __attribute__((address_space(1))) unsigned*)(g),                    \
      (__attribute__((address_space(3))) unsigned*)(l), 16, 0, 0)

__device__ inline unsigned short f2bf(float f) {
  union { float f; unsigned u; } uf; uf.f = f;
  unsigned u = uf.u;
  unsigned r = (u + 0x7fffu + ((u >> 16) & 1u)) >> 16;  // RNE
  return (unsigned short)r;
}

// ---------------- CSR build ----------------
// fused: zero cnt/cnt2 (all blocks) + int64-detect (block 0)
__global__ __launch_bounds__(256) void k_zero_detect(int* p, int n,
    const unsigned* rowsU32, int* flag) {
  int i = blockIdx.x * 256 + threadIdx.x;
  if (i < n) p[i] = 0;
  if (blockIdx.x == 0) {
    __shared__ int any;
    if (threadIdx.x == 0) any = 0;
    __syncthreads();
    if (rowsU32[2 * threadIdx.x + 1] != 0u) any = 1;
    __syncthreads();
    if (threadIdx.x == 0) *flag = (any == 0) ? 1 : 0;  // 1 => int64
  }
}

__device__ inline int edge_at(const void* p, int i, int is64) {
  return is64 ? (int)((const long long*)p)[i] : ((const int*)p)[i];
}

__global__ __launch_bounds__(256) void k_hist(const void* rows, const int* flag, int* cnt) {
  int i = blockIdx.x * 256 + threadIdx.x;
  if (i >= N_EDGES) return;
  int is64 = *flag;
  atomicAdd(&cnt[edge_at(rows, i, is64)], 1);
}

__global__ __launch_bounds__(256) void k_scan(const int* __restrict__ cnt, int* __restrict__ rp) {
  __shared__ int partial[256];
  const int T = 256;
  int t = threadIdx.x;
  int chunk = (N_NODES + T - 1) / T;
  int start = t * chunk;
  int end = start + chunk; if (end > N_NODES) end = N_NODES;
  int s = 0;
  for (int i = start; i < end && i >= start; ++i) s += cnt[i];
  partial[t] = (start < N_NODES) ? s : 0;
  __syncthreads();
  if (t == 0) {
    int acc = 0;
    for (int i = 0; i < T; ++i) { int v = partial[i]; partial[i] = acc; acc += v; }
  }
  __syncthreads();
  int acc = partial[t];
  for (int i = start; i < end && i >= start; ++i) { rp[i] = acc; acc += cnt[i]; }
  if (t == T - 1) rp[N_NODES] = acc;
}

__global__ __launch_bounds__(256) void k_scatter(const void* rows, const void* cols,
    const float* __restrict__ vals, const int* __restrict__ flag,
    const int* __restrict__ rp, int* cnt2, int* __restrict__ ccol, float* __restrict__ cval) {
  int i = blockIdx.x * 256 + threadIdx.x;
  if (i >= N_EDGES) return;
  int is64 = *flag;
  int r = edge_at(rows, i, is64);
  int c = edge_at(cols, i, is64);
  int pos = rp[r] + atomicAdd(&cnt2[r], 1);
  ccol[pos] = c;
  cval[pos] = vals[i];
}

// ---------------- fused f32 -> f16 for z, w1, w2, w3  +  bf16 pad-zero ----------------
#define Z4   160000
#define W14  2048
#define W24  8192
#define W34  32768
#define PADZ 15360   // (PADM - N_NODES) * 512 / 8
__global__ __launch_bounds__(256) void k_f2h_all(const float* __restrict__ z, const float* __restrict__ w1,
    const float* __restrict__ w2, const float* __restrict__ w3,
    _Float16* __restrict__ zh, _Float16* __restrict__ w1h,
    _Float16* __restrict__ w2h, _Float16* __restrict__ w3h,
    unsigned short* __restrict__ xb) {
  int t = blockIdx.x * 256 + threadIdx.x;
  const float* src; _Float16* dst; int idx;
  if (t < Z4)                        { src = z;  dst = zh;  idx = t; }
  else if (t < Z4 + W14)             { src = w1; dst = w1h; idx = t - Z4; }
  else if (t < Z4 + W14 + W24)       { src = w2; dst = w2h; idx = t - Z4 - W14; }
  else if (t < Z4 + W14 + W24 + W34) { src = w3; dst = w3h; idx = t - Z4 - W14 - W24; }
  else if (t < Z4 + W14 + W24 + W34 + PADZ) {
    const int pt = t - Z4 - W14 - W24 - W34;
    uint4 zz; zz.x = zz.y = zz.z = zz.w = 0u;
    *(uint4*)&xb[(size_t)N_NODES * 512 + (size_t)pt * 8] = zz;
    return;
  } else return;
  const float4 f = *(const float4*)(src + (size_t)idx * 4);
  half4 h;
  h[0] = (_Float16)f.x; h[1] = (_Float16)f.y; h[2] = (_Float16)f.z; h[3] = (_Float16)f.w;
  *(half4*)(dst + (size_t)idx * 4) = h;
}

// ---------------- fp16 MFMA linear, BK=64: outh = leaky(A[M,K] @ W[Dout,K]^T) ----------------
template <int K>
__global__ __launch_bounds__(256) void k_linh(const _Float16* __restrict__ A,
    const _Float16* __restrict__ W, _Float16* __restrict__ outh,
    int M, int Dout, const int* __restrict__ activeFlag) {
  __shared__ __align__(16) unsigned short As[128 * 64];
  __shared__ __align__(16) unsigned short Bs[128 * 64];
  const int tid = threadIdx.x;
  const int m0 = blockIdx.x * 128, n0 = blockIdx.y * 128;
  const int wave = tid >> 6, lane = tid & 63;
  const int wm = (wave >> 1) << 6;
  const int wn = (wave & 1) << 6;
  const int lr = lane & 15;
  const int lko = (lane >> 4) << 3;

  const int lrow8 = lane >> 3;          // 0..7 within chunk
  const int lcol  = (lane & 7) << 3;    // 0,8,..,56 halfs
  int arows[4]; const _Float16* gb[4];
  unsigned short *la[4], *lb[4];
#pragma unroll
  for (int j = 0; j < 4; ++j) {
    const int c = wave * 4 + j;
    int ar = m0 + c * 8 + lrow8; if (ar > M - 1) ar = M - 1;   // clamp; stores guarded
    arows[j] = ar;
    gb[j] = W + (size_t)(n0 + c * 8 + lrow8) * K + lcol;
    la[j] = &As[c * 512];
    lb[j] = &Bs[c * 512];
  }

  f32x4 acc[4][4];
#pragma unroll
  for (int i = 0; i < 4; ++i)
#pragma unroll
    for (int j = 0; j < 4; ++j)
#pragma unroll
      for (int q = 0; q < 4; ++q) acc[i][j][q] = 0.f;

  for (int k0 = 0; k0 < K; k0 += 64) {
    __syncthreads();
#pragma unroll
    for (int j = 0; j < 4; ++j) {
      GLOAD_LDS16(A + (size_t)arows[j] * K + k0 + lcol, la[j]);
      GLOAD_LDS16(gb[j] + k0, lb[j]);
    }
    __syncthreads();

#pragma unroll
    for (int kk = 0; kk < 64; kk += 32) {
      f16x8 af[4], bff[4];
#pragma unroll
      for (int f = 0; f < 4; ++f) {
        af[f]  = *(const f16x8*)&As[(wm + f * 16 + lr) * 64 + kk + lko];
        bff[f] = *(const f16x8*)&Bs[(wn + f * 16 + lr) * 64 + kk + lko];
      }
#pragma unroll
      for (int mi = 0; mi < 4; ++mi)
#pragma unroll
        for (int ni = 0; ni < 4; ++ni)
          acc[mi][ni] = __builtin_amdgcn_mfma_f32_16x16x32_f16(af[mi], bff[ni], acc[mi][ni], 0, 0, 0);
    }
  }

  const bool act = (*activeFlag) != 0;
#pragma unroll
  for (int mi = 0; mi < 4; ++mi) {
#pragma unroll
    for (int ni = 0; ni < 4; ++ni) {
      const int col = n0 + wn + ni * 16 + lr;
      const int rbase = m0 + wm + mi * 16 + ((lane >> 4) << 2);
#pragma unroll
      for (int q = 0; q < 4; ++q) {
        const int rr = rbase + q;
        if (rr < M) {
          float v = acc[mi][ni][q];
          if (act && v < 0.f) v *= 0.01f;
          outh[(size_t)rr * Dout + col] = (_Float16)v;
        }
      }
    }
  }
}

// ---------------- CSR spmm, fp16 gathers ----------------
// D=128: 2 rows per block, one wave (64 lanes) per row, half2 per lane, 2-edge ILP
__global__ __launch_bounds__(128) void k_spmm_d128(const int* __restrict__ rp,
    const int* __restrict__ ccol, const float* __restrict__ cval,
    const _Float16* __restrict__ sup, _Float16* __restrict__ outh) {
  const int wid = threadIdx.x >> 6;
  const int lane = threadIdx.x & 63;
  const int r = blockIdx.x * 2 + wid;
  const int d0 = lane * 2;
  const int s = rp[r], e = rp[r + 1];
  float a0x = 0.f, a0y = 0.f, a1x = 0.f, a1y = 0.f;
  int i = s;
  for (; i + 1 < e; i += 2) {
    const float w0 = cval[i], w1 = cval[i + 1];
    const half2 x0 = *(const half2*)(sup + (size_t)ccol[i] * 128 + d0);
    const half2 x1 = *(const half2*)(sup + (size_t)ccol[i + 1] * 128 + d0);
    a0x = fmaf(w0, (float)x0[0], a0x); a0y = fmaf(w0, (float)x0[1], a0y);
    a1x = fmaf(w1, (float)x1[0], a1x); a1y = fmaf(w1, (float)x1[1], a1y);
  }
  if (i < e) {
    const float w0 = cval[i];
    const half2 x0 = *(const half2*)(sup + (size_t)ccol[i] * 128 + d0);
    a0x = fmaf(w0, (float)x0[0], a0x); a0y = fmaf(w0, (float)x0[1], a0y);
  }
  half2 h; h[0] = (_Float16)(a0x + a1x); h[1] = (_Float16)(a0y + a1y);
  *(half2*)(outh + (size_t)r * 128 + d0) = h;
}

// D=256: one row per 128-thread block, half2 per thread, 4-edge ILP
__global__ __launch_bounds__(128) void k_spmm_d256(const int* __restrict__ rp,
    const int* __restrict__ ccol, const float* __restrict__ cval,
    const _Float16* __restrict__ sup, _Float16* __restrict__ outh) {
  const int r = blockIdx.x;
  const int d0 = threadIdx.x * 2;
  const int s = rp[r], e = rp[r + 1];
  float ax[4] = {0.f, 0.f, 0.f, 0.f}, ay[4] = {0.f, 0.f, 0.f, 0.f};
  int i = s;
  for (; i + 3 < e; i += 4) {
#pragma unroll
    for (int c = 0; c < 4; ++c) {
      const float w = cval[i + c];
      const half2 x = *(const half2*)(sup + (size_t)ccol[i + c] * 256 + d0);
      ax[c] = fmaf(w, (float)x[0], ax[c]);
      ay[c] = fmaf(w, (float)x[1], ay[c]);
    }
  }
  for (; i < e; ++i) {
    const float w = cval[i];
    const half2 x = *(const half2*)(sup + (size_t)ccol[i] * 256 + d0);
    ax[0] = fmaf(w, (float)x[0], ax[0]);
    ay[0] = fmaf(w, (float)x[1], ay[0]);
  }
  half2 h;
  h[0] = (_Float16)((ax[0] + ax[1]) + (ax[2] + ax[3]));
  h[1] = (_Float16)((ay[0] + ay[1]) + (ay[2] + ay[3]));
  *(half2*)(outh + (size_t)r * 256 + d0) = h;
}

// D=512: one row per 128-thread block, half4 per thread, 4-edge ILP; writes fp32 xhat + bf16 xb
__global__ __launch_bounds__(128) void k_spmm_d512(const int* __restrict__ rp,
    const int* __restrict__ ccol, const float* __restrict__ cval,
    const _Float16* __restrict__ sup, float* __restrict__ outf,
    unsigned short* __restrict__ outb) {
  const int r = blockIdx.x;
  const int d0 = threadIdx.x * 4;
  const int s = rp[r], e = rp[r + 1];
  float a[4][4];
#pragma unroll
  for (int c = 0; c < 4; ++c)
#pragma unroll
    for (int v = 0; v < 4; ++v) a[c][v] = 0.f;
  int i = s;
  for (; i + 3 < e; i += 4) {
#pragma unroll
    for (int c = 0; c < 4; ++c) {
      const float w = cval[i + c];
      const half4 x = *(const half4*)(sup + (size_t)ccol[i + c] * 512 + d0);
#pragma unroll
      for (int v = 0; v < 4; ++v) a[c][v] = fmaf(w, (float)x[v], a[c][v]);
    }
  }
  for (; i < e; ++i) {
    const float w = cval[i];
    const half4 x = *(const half4*)(sup + (size_t)ccol[i] * 512 + d0);
#pragma unroll
    for (int v = 0; v < 4; ++v) a[0][v] = fmaf(w, (float)x[v], a[0][v]);
  }
  const float r0 = (a[0][0] + a[1][0]) + (a[2][0] + a[3][0]);
  const float r1 = (a[0][1] + a[1][1]) + (a[2][1] + a[3][1]);
  const float r2 = (a[0][2] + a[1][2]) + (a[2][2] + a[3][2]);
  const float r3 = (a[0][3] + a[1][3]) + (a[2][3] + a[3][3]);
  *(float4*)(outf + (size_t)r * 512 + d0) = make_float4(r0, r1, r2, r3);
  uint2 u;
  u.x = (unsigned)f2bf(r0) | ((unsigned)f2bf(r1) << 16);
  u.y = (unsigned)f2bf(r2) | ((unsigned)f2bf(r3) << 16);
  *(uint2*)(outb + (size_t)r * 512 + d0) = u;
}

// ---------------- final: adj = sigmoid(X @ X^T), 256^2 tile, 8 waves, BK=32 (32KB LDS), XCD swizzle ----------------
__global__ __launch_bounds__(512) void k_xxt3(const unsigned short* __restrict__ Xb,
                                              float* __restrict__ adj) {
  __shared__ __align__(16) unsigned short As[256 * 32];   // 16 KB
  __shared__ __align__(16) unsigned short Bs[256 * 32];   // 16 KB
  const int tid = threadIdx.x;

  // bijective chunked XCD swizzle: 1600 blocks, 1600 % 8 == 0
  const int bid = blockIdx.x;
  const int swz = (bid & 7) * 200 + (bid >> 3);
  const int m0 = (swz % 40) * 256;
  const int n0 = (swz / 40) * 256;

  const int wave = tid >> 6, lane = tid & 63;
  const int wm = (wave >> 2) << 7;   // 0 / 128
  const int wn = (wave & 3) << 6;    // 0 / 64 / 128 / 192
  const int lr = lane & 15;
  const int lko = (lane >> 4) << 3;  // 0,8,16,24

  // staging: chunk = 16 rows x 32 shorts (1 KB); 16 chunks per matrix; wave w: chunks 2w, 2w+1
  const int c0 = wave * 2;
  const int srow = c0 * 16 + (lane >> 2);      // 0..239 (+16 for second chunk)
  const int scol = (lane & 3) << 3;            // 0,8,16,24
  const unsigned short* gA0 = Xb + (size_t)(m0 + srow) * 512 + scol;
  const unsigned short* gA1 = gA0 + (size_t)16 * 512;
  const unsigned short* gB0 = Xb + (size_t)(n0 + srow) * 512 + scol;
  const unsigned short* gB1 = gB0 + (size_t)16 * 512;
  unsigned short* lA0 = &As[c0 * 512];
  unsigned short* lA1 = &As[(c0 + 1) * 512];
  unsigned short* lB0 = &Bs[c0 * 512];
  unsigned short* lB1 = &Bs[(c0 + 1) * 512];

  f32x4 acc[8][4];
#pragma unroll
  for (int i = 0; i < 8; ++i)
#pragma unroll
    for (int j = 0; j < 4; ++j)
#pragma unroll
      for (int q = 0; q < 4; ++q) acc[i][j][q] = 0.f;

  for (int k0 = 0; k0 < 512; k0 += 32) {
    __syncthreads();
    GLOAD_LDS16(gA0 + k0, lA0);
    GLOAD_LDS16(gA1 + k0, lA1);
    GLOAD_LDS16(gB0 + k0, lB0);
    GLOAD_LDS16(gB1 + k0, lB1);
    __syncthreads();

    bf16x8 bf[4];
#pragma unroll
    for (int ni = 0; ni < 4; ++ni)
      bf[ni] = *(const bf16x8*)&Bs[(wn + ni * 16 + lr) * 32 + lko];
#pragma unroll
    for (int mi = 0; mi < 8; ++mi) {
      const bf16x8 am = *(const bf16x8*)&As[(wm + mi * 16 + lr) * 32 + lko];
#pragma unroll
      for (int ni = 0; ni < 4; ++ni)
        acc[mi][ni] = __builtin_amdgcn_mfma_f32_16x16x32_bf16(am, bf[ni], acc[mi][ni], 0, 0, 0);
    }
  }

#pragma unroll
  for (int mi = 0; mi < 8; ++mi) {
#pragma unroll
    for (int ni = 0; ni < 4; ++ni) {
      const int col = n0 + wn + ni * 16 + lr;
      const int rbase = m0 + wm + mi * 16 + ((lane >> 4) << 2);
      if (col < N_NODES) {
#pragma unroll
        for (int q = 0; q < 4; ++q) {
          const int rr = rbase + q;
          if (rr < N_NODES) {
            const float s = acc[mi][ni][q];
            const float sg = __builtin_amdgcn_rcpf(1.0f + __expf(-s));
            __builtin_nontemporal_store(sg, &adj[(size_t)rr * N_NODES + col]);
          }
        }
      }
    }
  }
}

// ================= fp32 fallback path (used only if ws too small) =================
template <int K>
__global__ __launch_bounds__(256) void k_linear(const float* __restrict__ A,
    const float* __restrict__ W, float* __restrict__ C,
    int M, int Dout, const int* __restrict__ activeFlag) {
  __shared__ __align__(16) float As[16][68];
  __shared__ __align__(16) float Ws[16][68];
  const int m0 = blockIdx.x * 64;
  const int n0 = blockIdx.y * 64;
  const int tid = threadIdx.x;
  const int tx = tid & 15, ty = tid >> 4;
  const int lrow = tid >> 2;
  const int lk = (tid & 3) * 4;
  float acc[4][4];
#pragma unroll
  for (int i = 0; i < 4; ++i)
#pragma unroll
    for (int j = 0; j < 4; ++j) acc[i][j] = 0.f;

  for (int k0 = 0; k0 < K; k0 += 16) {
    float4 va = make_float4(0.f, 0.f, 0.f, 0.f);
    if (m0 + lrow < M) va = *(const float4*)(A + (size_t)(m0 + lrow) * K + k0 + lk);
    float4 vb = *(const float4*)(W + (size_t)(n0 + lrow) * K + k0 + lk);
    __syncthreads();
    As[lk + 0][lrow] = va.x; As[lk + 1][lrow] = va.y; As[lk + 2][lrow] = va.z; As[lk + 3][lrow] = va.w;
    Ws[lk + 0][lrow] = vb.x; Ws[lk + 1][lrow] = vb.y; Ws[lk + 2][lrow] = vb.z; Ws[lk + 3][lrow] = vb.w;
    __syncthreads();
#pragma unroll
    for (int kk = 0; kk < 16; ++kk) {
      const float4 a4 = *(const float4*)&As[kk][ty << 2];
      const float4 b4 = *(const float4*)&Ws[kk][tx << 2];
      const float av[4] = {a4.x, a4.y, a4.z, a4.w};
      const float bv[4] = {b4.x, b4.y, b4.z, b4.w};
#pragma unroll
      for (int i = 0; i < 4; ++i)
#pragma unroll
        for (int j = 0; j < 4; ++j) acc[i][j] = fmaf(av[i], bv[j], acc[i][j]);
    }
  }
  const bool act = (*activeFlag) != 0;
#pragma unroll
  for (int i = 0; i < 4; ++i) {
    const int row = m0 + (ty << 2) + i;
    if (row < M) {
#pragma unroll
      for (int j = 0; j < 4; ++j) {
        float v = acc[i][j];
        if (act && v < 0.f) v *= 0.01f;
        C[(size_t)row * Dout + n0 + (tx << 2) + j] = v;
      }
    }
  }
}

template <int D>
__global__ __launch_bounds__(128) void k_spmm2(const int* __restrict__ rp,
    const int* __restrict__ ccol, const float* __restrict__ cval,
    const float* __restrict__ sup, float* __restrict__ out) {
  constexpr int V = D / 128;
  const int r = blockIdx.x;
  const int d0 = threadIdx.x * V;
  const int s = rp[r], e = rp[r + 1];
  float acc[V];
#pragma unroll
  for (int v = 0; v < V; ++v) acc[v] = 0.f;
  for (int i = s; i < e; ++i) {
    const float w = cval[i];
    const float* src = sup + (size_t)ccol[i] * D + d0;
    if constexpr (V == 4) {
      const float4 x = *(const float4*)src;
      acc[0] = fmaf(w, x.x, acc[0]); acc[1] = fmaf(w, x.y, acc[1]);
      acc[2] = fmaf(w, x.z, acc[2]); acc[3] = fmaf(w, x.w, acc[3]);
    } else if constexpr (V == 2) {
      const float2 x = *(const float2*)src;
      acc[0] = fmaf(w, x.x, acc[0]); acc[1] = fmaf(w, x.y, acc[1]);
    } else {
      acc[0] = fmaf(w, *src, acc[0]);
    }
  }
  float* dst = out + (size_t)r * D + d0;
  if constexpr (V == 4) *(float4*)dst = make_float4(acc[0], acc[1], acc[2], acc[3]);
  else if constexpr (V == 2) *(float2*)dst = make_float2(acc[0], acc[1]);
  else *dst = acc[0];
}

__global__ __launch_bounds__(256) void k_xxt_f32(const float* __restrict__ Xf, float* __restrict__ adj) {
  __shared__ __align__(16) short As[128 * 32];
  __shared__ __align__(16) short Bs[128 * 32];
  const int tid = threadIdx.x;
  const int m0 = blockIdx.x * 128, n0 = blockIdx.y * 128;
  const int wave = tid >> 6, lane = tid & 63;
  const int wm = (wave >> 1) << 6;
  const int wn = (wave & 1) << 6;
  const int lr = lane & 15;
  const int lko = (lane >> 4) << 3;

  f32x4 acc[4][4];
#pragma unroll
  for (int i = 0; i < 4; ++i)
#pragma unroll
    for (int j = 0; j < 4; ++j)
#pragma unroll
      for (int q = 0; q < 4; ++q) acc[i][j][q] = 0.f;

  for (int k0 = 0; k0 < 512; k0 += 32) {
    __syncthreads();
#pragma unroll
    for (int h = 0; h < 2; ++h) {
      const int c = tid + h * 256;
      const int row = c >> 2;
      const int cq = (c & 3) << 3;
      float4 fa0 = make_float4(0, 0, 0, 0), fa1 = fa0, fb0 = fa0, fb1 = fa0;
      const int ga = m0 + row, gb = n0 + row;
      if (ga < N_NODES) {
        fa0 = *(const float4*)(Xf + (size_t)ga * 512 + k0 + cq);
        fa1 = *(const float4*)(Xf + (size_t)ga * 512 + k0 + cq + 4);
      }
      if (gb < N_NODES) {
        fb0 = *(const float4*)(Xf + (size_t)gb * 512 + k0 + cq);
        fb1 = *(const float4*)(Xf + (size_t)gb * 512 + k0 + cq + 4);
      }
      uint4 ua, ub;
      ua.x = (unsigned)f2bf(fa0.x) | ((unsigned)f2bf(fa0.y) << 16);
      ua.y = (unsigned)f2bf(fa0.z) | ((unsigned)f2bf(fa0.w) << 16);
      ua.z = (unsigned)f2bf(fa1.x) | ((unsigned)f2bf(fa1.y) << 16);
      ua.w = (unsigned)f2bf(fa1.z) | ((unsigned)f2bf(fa1.w) << 16);
      ub.x = (unsigned)f2bf(fb0.x) | ((unsigned)f2bf(fb0.y) << 16);
      ub.y = (unsigned)f2bf(fb0.z) | ((unsigned)f2bf(fb0.w) << 16);
      ub.z = (unsigned)f2bf(fb1.x) | ((unsigned)f2bf(fb1.y) << 16);
      ub.w = (unsigned)f2bf(fb1.z) | ((unsigned)f2bf(fb1.w) << 16);
      *(uint4*)&As[row * 32 + cq] = ua;
      *(uint4*)&Bs[row * 32 + cq] = ub;
    }
    __syncthreads();

    bf16x8 af[4], bff[4];
#pragma unroll
    for (int f = 0; f < 4; ++f) {
      af[f]  = *(const bf16x8*)&As[(wm + f * 16 + lr) * 32 + lko];
      bff[f] = *(const bf16x8*)&Bs[(wn + f * 16 + lr) * 32 + lko];
    }
#pragma unroll
    for (int mi = 0; mi < 4; ++mi)
#pragma unroll
      for (int ni = 0; ni < 4; ++ni)
        acc[mi][ni] = __builtin_amdgcn_mfma_f32_16x16x32_bf16(af[mi], bff[ni], acc[mi][ni], 0, 0, 0);
  }

#pragma unroll
  for (int mi = 0; mi < 4; ++mi) {
#pragma unroll
    for (int ni = 0; ni < 4; ++ni) {
      const int col = n0 + wn + ni * 16 + lr;
      const int rbase = m0 + wm + mi * 16 + ((lane >> 4) << 2);
      if (col < N_NODES) {
#pragma unroll
        for (int q = 0; q < 4; ++q) {
          const int rr = rbase + q;
          if (rr < N_NODES) {
            const float s = acc[mi][ni][q];
            adj[(size_t)rr * N_NODES + col] = 1.0f / (1.0f + __expf(-s));
          }
        }
      }
    }
  }
}

// ---------------- host ----------------
extern "C" void kernel_launch(void* const* d_in, const int* in_sizes, int n_in,
                              void* d_out, int out_size, void* d_ws, size_t ws_size,
                              hipStream_t stream) {
  const float* z     = (const float*)d_in[0];
  const void*  arow  = d_in[1];
  const void*  acol  = d_in[2];
  const float* avals = (const float*)d_in[3];
  const float* w1    = (const float*)d_in[4];
  const float* w2    = (const float*)d_in[5];
  const float* w3    = (const float*)d_in[6];
  const int*   activ = (const int*)d_in[7];

  float* out  = (float*)d_out;
  float* xhat = out;                                  // [10000,512]
  float* adj  = out + (size_t)N_NODES * DOUT3;        // [10000,10000]

  // int scratch inside the adj region (dead before k_xxt overwrites it)
  int* iscr  = (int*)(adj + 9000000);
  int* rp    = iscr;                       // 10001 (pad 10016)
  int* cnt   = rp + 10016;
  int* cnt2  = cnt + 10016;
  int* flag  = cnt2 + 10016;               // 1 (pad 16)
  int* ccol  = flag + 16;                  // E
  float* cval = (float*)(ccol + N_EDGES);  // E

  // fp16 scratch in d_ws
  _Float16* wsh = (_Float16*)d_ws;
  size_t off = 0;
  unsigned short* xb = (unsigned short*)d_ws;             off += (size_t)PADM * 512;  // bf16 x_hat
  _Float16* zh  = wsh + off;  off += 640000;
  _Float16* w1h = wsh + off;  off += 8192;
  _Float16* w2h = wsh + off;  off += 32768;
  _Float16* w3h = wsh + off;  off += 131072;
  _Float16* suph = wsh + off; off += (size_t)N_NODES * 512;
  _Float16* x1h = wsh + off;  off += (size_t)N_NODES * 128;
  _Float16* x2h = wsh + off;  off += (size_t)N_NODES * 256;
  const bool useWs = (ws_size >= off * sizeof(_Float16));

  // CSR build (fused zero+detect)
  k_zero_detect<<<(20032 + 255) / 256, 256, 0, stream>>>(cnt, 20032, (const unsigned*)arow, flag);
  k_hist<<<(N_EDGES + 255) / 256, 256, 0, stream>>>(arow, flag, cnt);
  k_scan<<<1, 256, 0, stream>>>(cnt, rp);
  k_scatter<<<(N_EDGES + 255) / 256, 256, 0, stream>>>(arow, acol, avals, flag, rp, cnt2, ccol, cval);

  if (useWs) {
    // convert inputs to fp16 + zero bf16 pad rows (single fused launch)
    k_f2h_all<<<(Z4 + W14 + W24 + W34 + PADZ + 255) / 256, 256, 0, stream>>>(
        z, w1, w2, w3, zh, w1h, w2h, w3h, xb);

    // layer 1
    k_linh<64><<<dim3(79, 1), 256, 0, stream>>>(zh, w1h, suph, N_NODES, 128, activ);
    k_spmm_d128<<<N_NODES / 2, 128, 0, stream>>>(rp, ccol, cval, suph, x1h);
    // layer 2
    k_linh<128><<<dim3(79, 2), 256, 0, stream>>>(x1h, w2h, suph, N_NODES, 256, activ);
    k_spmm_d256<<<N_NODES, 128, 0, stream>>>(rp, ccol, cval, suph, x2h);
    // layer 3
    k_linh<256><<<dim3(79, 4), 256, 0, stream>>>(x2h, w3h, suph, N_NODES, 512, activ);
    k_spmm_d512<<<N_NODES, 128, 0, stream>>>(rp, ccol, cval, suph, xhat, xb);

    k_xxt3<<<1600, 512, 0, stream>>>(xb, adj);
  } else {
    // fp32 fallback (scratch in adj region)
    float* sup = adj;
    float* x1  = adj + 5120000;
    float* x2  = x1 + 1280000;
    k_linear<64><<<dim3(157, 2), 256, 0, stream>>>(z, w1, sup, N_NODES, 128, activ);
    k_spmm2<128><<<N_NODES, 128, 0, stream>>>(rp, ccol, cval, sup, x1);
    k_linear<128><<<dim3(157, 4), 256, 0, stream>>>(x1, w2, sup, N_NODES, 256, activ);
    k_spmm2<256><<<N_NODES, 128, 0, stream>>>(rp, ccol, cval, sup, x2);
    k_linear<256><<<dim3(157, 8), 256, 0, stream>>>(x2, w3, sup, N_NODES, 512, activ);
    k_spmm2<512><<<N_NODES, 128, 0, stream>>>(rp, ccol, cval, sup, xhat);
    k_xxt_f32<<<dim3(79, 79), 256, 0, stream>>>(xhat, adj);
  }
}